// Round 9
// baseline (846.854 us; speedup 1.0000x reference)
//
#include <hip/hip_runtime.h>

// Problem constants (match reference)
constexpr int B_  = 2;
constexpr int L_  = 1024;
constexpr int D_  = 768;
constexpr int E_  = 1536;
constexpr int N_  = 16;
constexpr int R_  = 48;
constexpr int NL_ = 4;
constexpr int NC_ = 5;
constexpr int M_  = B_ * L_;        // 2048 token rows
constexpr int E2_ = 2 * E_;         // 3072
constexpr int XD_ = R_ + 2 * N_;    // 80
constexpr float EPS_ = 1e-5f;

constexpr int NCH_ = 16;            // time-chunks for parallel scan
constexpr int CL_  = L_ / NCH_;     // 64 timesteps per chunk
constexpr int KS_  = 8;             // split-K factor for xproj GEMM
constexpr int XSL_ = E_ / KS_;      // 192 K-slice
constexpr int USTR_ = 200;          // padded LDS row stride (ushorts)
constexpr int NMB_ = M_ / 64;       // 32 row-groups for xproj split-K

typedef __attribute__((ext_vector_type(8))) short bf16x8;
typedef __attribute__((ext_vector_type(4))) float f32x4;
typedef const __attribute__((address_space(1))) void* gas_t;
typedef __attribute__((address_space(3))) void* las_t;

__device__ __forceinline__ float sigm(float x) { return 1.0f / (1.0f + __expf(-x)); }
__device__ __forceinline__ float softplusf(float x) { return x > 20.0f ? x : log1pf(__expf(x)); }
__device__ __forceinline__ ushort f2b(float f) {  // fp32 -> bf16 RNE
  union { float f; unsigned u; } v; v.f = f;
  unsigned r = (v.u + 0x7fffu + ((v.u >> 16) & 1u)) >> 16;
  return (ushort)r;
}
__device__ __forceinline__ float b2f(ushort u) {
  union { unsigned u; float f; } v; v.u = ((unsigned)u) << 16;
  return v.f;
}
__device__ __forceinline__ float b2f_lo(unsigned p) {
  union { unsigned u; float f; } v; v.u = p << 16;
  return v.f;
}
__device__ __forceinline__ float b2f_hi(unsigned p) {
  union { unsigned u; float f; } v; v.u = p & 0xffff0000u;
  return v.f;
}

// DPP row_ror add: sum over 16-lane rows, full-rate VALU
template <int CTRL>
__device__ __forceinline__ float dpp_add(float x) {
  int yi = __builtin_amdgcn_update_dpp(0, __builtin_bit_cast(int, x), CTRL, 0xf, 0xf, false);
  return x + __builtin_bit_cast(float, yi);
}
__device__ __forceinline__ float row_sum16(float x) {
  x = dpp_add<0x121>(x);
  x = dpp_add<0x122>(x);
  x = dpp_add<0x124>(x);
  x = dpp_add<0x128>(x);
  return x;
}

__device__ __forceinline__ float block_sum(float v, float* sm) {
  #pragma unroll
  for (int o = 32; o > 0; o >>= 1) v += __shfl_xor(v, o);
  if ((threadIdx.x & 63) == 0) sm[threadIdx.x >> 6] = v;
  __syncthreads();
  return sm[0] + sm[1] + sm[2] + sm[3];
}

// One-shot weight prep: in_w, out_w, xproj_w plain f2b; dt_w padded 48->64.
// Also zeroes the split-K completion counters (ws is re-poisoned every launch).
constexpr int WS1_ = NL_ * E2_ * D_;
constexpr int WS2_ = NL_ * D_ * E_;
constexpr int WS3_ = NL_ * XD_ * E_;
constexpr int WS4_ = NL_ * E_ * 64;
__global__ __launch_bounds__(256) void k_wprep(const float* __restrict__ in_w, const float* __restrict__ out_w,
                                               const float* __restrict__ xw, const float* __restrict__ dw,
                                               ushort* __restrict__ in_wb, ushort* __restrict__ out_wb,
                                               ushort* __restrict__ xwb, ushort* __restrict__ dtwb,
                                               int* __restrict__ cnt) {
  if (blockIdx.x == 0 && threadIdx.x < NL_ * NMB_) cnt[threadIdx.x] = 0;
  int i = (blockIdx.x * 256 + threadIdx.x) * 4;
  if (i < WS1_) {
    float4 v = *(const float4*)(in_w + i);
    *(ushort4*)(in_wb + i) = make_ushort4(f2b(v.x), f2b(v.y), f2b(v.z), f2b(v.w));
  } else if (i < WS1_ + WS2_) {
    int j = i - WS1_;
    float4 v = *(const float4*)(out_w + j);
    *(ushort4*)(out_wb + j) = make_ushort4(f2b(v.x), f2b(v.y), f2b(v.z), f2b(v.w));
  } else if (i < WS1_ + WS2_ + WS3_) {
    int j = i - WS1_ - WS2_;
    float4 v = *(const float4*)(xw + j);
    *(ushort4*)(xwb + j) = make_ushort4(f2b(v.x), f2b(v.y), f2b(v.z), f2b(v.w));
  } else if (i < WS1_ + WS2_ + WS3_ + WS4_) {
    int j = i - WS1_ - WS2_ - WS3_;
    int k = j & 63, e = j >> 6;
    ushort4 o;
    o.x = (k + 0 < R_) ? f2b(dw[e * R_ + k + 0]) : (ushort)0;
    o.y = (k + 1 < R_) ? f2b(dw[e * R_ + k + 1]) : (ushort)0;
    o.z = (k + 2 < R_) ? f2b(dw[e * R_ + k + 2]) : (ushort)0;
    o.w = (k + 3 < R_) ? f2b(dw[e * R_ + k + 3]) : (ushort)0;
    *(ushort4*)(dtwb + j) = o;
  }
}

// h[m,d] = x[m,:12] @ proj_w[d,:12] + proj_b[d]
__global__ __launch_bounds__(256) void k_proj(const float* __restrict__ x, const float* __restrict__ pw,
                                              const float* __restrict__ pb, float* __restrict__ h) {
  __shared__ float xs[12];
  int m = blockIdx.y;
  int d = blockIdx.x * 256 + threadIdx.x;
  if (threadIdx.x < 12) xs[threadIdx.x] = x[m * 12 + threadIdx.x];
  __syncthreads();
  float acc = pb[d];
  #pragma unroll
  for (int j = 0; j < 12; j++) acc = fmaf(xs[j], pw[d * 12 + j], acc);
  h[(size_t)m * D_ + d] = acc;
}

// hn_bf16[m,:] = rmsnorm(h[m,:]) * w
__global__ __launch_bounds__(256) void k_rmsnorm_bf(const float* __restrict__ h, const float* __restrict__ w,
                                                    ushort* __restrict__ hn) {
  __shared__ float sm[4];
  int m = blockIdx.x, tid = threadIdx.x;
  const float* row = h + (size_t)m * D_;
  float v0 = row[tid], v1 = row[tid + 256], v2 = row[tid + 512];
  float s = block_sum(v0 * v0 + v1 * v1 + v2 * v2, sm);
  float sc = rsqrtf(s * (1.0f / D_) + EPS_);
  ushort* o = hn + (size_t)m * D_;
  o[tid]       = f2b(v0 * sc * w[tid]);
  o[tid + 256] = f2b(v1 * sc * w[tid + 256]);
  o[tid + 512] = f2b(v2 * sc * w[tid + 512]);
}

// C[M,Nd] = A_bf16[M,Kd] @ Bw_bf16[Nd,Kd]^T. MFMA 16x16x32 bf16.
// MODE 1: fp32 C=v+res[off]
// MODE 4: in-proj split epilogue: cols<E -> bf16 u-proj[M][E]; cols>=E -> silu -> bf16 Cv2[M][E]
// MODE 6: bf16 C=softplus(v+res[col]) (dt)
template <int BM, int BN, int MODE>
__global__ __launch_bounds__(256) void k_gemm_bf(const ushort* __restrict__ A, const ushort* __restrict__ Bw,
                                                 void* __restrict__ Cv, const float* __restrict__ res,
                                                 void* __restrict__ Cv2, int Kd, int Nd) {
  constexpr int AM = BM / 32, BNF = BN / 32;
  __shared__ ushort sA[BM * 32];
  __shared__ ushort sB[BN * 32];
  const int tid = threadIdx.x;
  const int wave = tid >> 6, lane = tid & 63;
  const int q = lane >> 4, r = lane & 15;
  const int wm = wave >> 1, wn = wave & 1;
  const int m0 = blockIdx.y * BM, n0 = blockIdx.x * BN;
  f32x4 acc[AM][BNF] = {};

  for (int k0 = 0; k0 < Kd; k0 += 32) {
    #pragma unroll
    for (int j = 0; j < BM / 64; j++) {
      int i = j * 256 + tid;
      const ushort* gp = A + (size_t)(m0 + (i >> 2)) * Kd + k0 + ((i & 3) << 3);
      __builtin_amdgcn_global_load_lds((gas_t)gp, (las_t)(sA + ((j * 256 + wave * 64) << 3)), 16, 0, 0);
    }
    #pragma unroll
    for (int j = 0; j < BN / 64; j++) {
      int i = j * 256 + tid;
      const ushort* gp = Bw + (size_t)(n0 + (i >> 2)) * Kd + k0 + ((i & 3) << 3);
      __builtin_amdgcn_global_load_lds((gas_t)gp, (las_t)(sB + ((j * 256 + wave * 64) << 3)), 16, 0, 0);
    }
    __syncthreads();
    bf16x8 af[AM], bfv[BNF];
    #pragma unroll
    for (int mi = 0; mi < AM; mi++)
      af[mi] = *(const bf16x8*)&sA[(wm * (BM / 2) + mi * 16 + r) * 32 + q * 8];
    #pragma unroll
    for (int nj = 0; nj < BNF; nj++)
      bfv[nj] = *(const bf16x8*)&sB[(wn * (BN / 2) + nj * 16 + r) * 32 + q * 8];
    #pragma unroll
    for (int mi = 0; mi < AM; mi++)
      #pragma unroll
      for (int nj = 0; nj < BNF; nj++)
        acc[mi][nj] = __builtin_amdgcn_mfma_f32_16x16x32_bf16(af[mi], bfv[nj], acc[mi][nj], 0, 0, 0);
    __syncthreads();
  }
  // C/D layout: col = lane&15, row = (lane>>4)*4 + reg
  #pragma unroll
  for (int mi = 0; mi < AM; mi++) {
    #pragma unroll
    for (int nj = 0; nj < BNF; nj++) {
      int col = n0 + wn * (BN / 2) + nj * 16 + r;
      #pragma unroll
      for (int rg = 0; rg < 4; rg++) {
        int row = m0 + wm * (BM / 2) + mi * 16 + q * 4 + rg;
        float v = acc[mi][nj][rg];
        if (MODE == 4) {
          if (col >= E_) {
            v = v * sigm(v);
            ((ushort*)Cv2)[(size_t)row * E_ + col - E_] = f2b(v);
          } else {
            ((ushort*)Cv)[(size_t)row * E_ + col] = f2b(v);
          }
        } else if (MODE == 6) {
          ((ushort*)Cv)[(size_t)row * Nd + col] = f2b(softplusf(v + res[col]));
        } else {
          size_t off = (size_t)row * Nd + col;
          if (MODE == 1) v += res[off];
          ((float*)Cv)[off] = v;
        }
      }
    }
  }
}

// Fused conv+silu+xproj GEMM (split-K) with last-arriving-block combine.
// Block (mb, ks): computes u tile, partial GEMM; the 8th finisher per mb sums
// partials -> xdbc fp32 [M][80] + bf16 dt-input copy [M][64].
__global__ __launch_bounds__(256) void k_gemm_xc(const ushort* __restrict__ proju, const float* __restrict__ cw,
                                                 const float* __restrict__ cb, const ushort* __restrict__ Bw,
                                                 ushort* __restrict__ ub16, float* __restrict__ part,
                                                 int* __restrict__ cnt, float* __restrict__ xdbc,
                                                 ushort* __restrict__ xb) {
  __shared__ ushort sU[64 * USTR_];   // 25.6 KB
  __shared__ ushort sB[80 * USTR_];   // 32 KB
  const int tid = threadIdx.x;
  const int wave = tid >> 6, lane = tid & 63;
  const int q = lane >> 4, r = lane & 15;
  const int m0 = blockIdx.x * 64;
  const int kbeg = blockIdx.y * XSL_;

  // stage xproj weight slice: 80 rows x 192 ushorts
  for (int i = tid; i < 80 * (XSL_ / 8); i += 256) {
    int row = i / (XSL_ / 8), seg = i % (XSL_ / 8);
    bf16x8 v = *(const bf16x8*)(Bw + (size_t)row * E_ + kbeg + seg * 8);
    *(bf16x8*)&sB[row * USTR_ + seg * 8] = v;
  }

  // conv+silu for the u tile: 64 rows x 48 e4-groups, 12 per thread
  for (int i = tid; i < 64 * (XSL_ / 4); i += 256) {
    int row = i / (XSL_ / 4), e4i = i % (XSL_ / 4);
    int e = kbeg + e4i * 4;
    int m = m0 + row;
    int t = m & (L_ - 1);
    float4 w0 = *(const float4*)(cw + (e + 0) * 4);
    float4 w1 = *(const float4*)(cw + (e + 1) * 4);
    float4 w2 = *(const float4*)(cw + (e + 2) * 4);
    float4 w3 = *(const float4*)(cw + (e + 3) * 4);
    float wv[4][4] = {{w0.x, w0.y, w0.z, w0.w}, {w1.x, w1.y, w1.z, w1.w},
                      {w2.x, w2.y, w2.z, w2.w}, {w3.x, w3.y, w3.z, w3.w}};
    float4 bb = *(const float4*)(cb + e);
    float acc[4] = {bb.x, bb.y, bb.z, bb.w};
    #pragma unroll
    for (int k = 0; k < 4; k++) {
      int tt = t + k - 3;
      if (tt >= 0) {
        uint2 p = *(const uint2*)(proju + (size_t)(m + k - 3) * E_ + e);
        acc[0] = fmaf(wv[0][k], b2f_lo(p.x), acc[0]);
        acc[1] = fmaf(wv[1][k], b2f_hi(p.x), acc[1]);
        acc[2] = fmaf(wv[2][k], b2f_lo(p.y), acc[2]);
        acc[3] = fmaf(wv[3][k], b2f_hi(p.y), acc[3]);
      }
    }
    float u0 = acc[0] * sigm(acc[0]), u1 = acc[1] * sigm(acc[1]);
    float u2 = acc[2] * sigm(acc[2]), u3 = acc[3] * sigm(acc[3]);
    uint2 uo;
    uo.x = (unsigned)f2b(u0) | ((unsigned)f2b(u1) << 16);
    uo.y = (unsigned)f2b(u2) | ((unsigned)f2b(u3) << 16);
    *(uint2*)(ub16 + (size_t)m * E_ + e) = uo;
    *(uint2*)&sU[row * USTR_ + e4i * 4] = uo;
  }
  __syncthreads();

  f32x4 acc[5] = {};
  #pragma unroll
  for (int k0 = 0; k0 < XSL_ / 32; k0++) {
    bf16x8 af = *(const bf16x8*)&sU[(wave * 16 + r) * USTR_ + k0 * 32 + q * 8];
    #pragma unroll
    for (int nj = 0; nj < 5; nj++) {
      bf16x8 bfv = *(const bf16x8*)&sB[(nj * 16 + r) * USTR_ + k0 * 32 + q * 8];
      acc[nj] = __builtin_amdgcn_mfma_f32_16x16x32_bf16(af, bfv, acc[nj], 0, 0, 0);
    }
  }
  float* pp = part + (size_t)blockIdx.y * M_ * XD_;
  #pragma unroll
  for (int nj = 0; nj < 5; nj++) {
    int col = nj * 16 + r;
    #pragma unroll
    for (int rg = 0; rg < 4; rg++) {
      int row = m0 + wave * 16 + q * 4 + rg;
      pp[(size_t)row * XD_ + col] = acc[nj][rg];
    }
  }

  // last-arriving-block combine for this row-group (release/acquire via threadfence)
  __syncthreads();
  __shared__ int s_last;
  if (tid == 0) {
    __threadfence();
    s_last = atomicAdd(cnt + blockIdx.x, 1);
  }
  __syncthreads();
  if (s_last == KS_ - 1) {
    __threadfence();
    for (int i = tid; i < 64 * XD_; i += 256) {
      int row = m0 + i / XD_, col = i % XD_;
      float s = 0.0f;
      #pragma unroll
      for (int ks = 0; ks < KS_; ks++) s += part[(size_t)ks * M_ * XD_ + (size_t)row * XD_ + col];
      xdbc[(size_t)row * XD_ + col] = s;
      if (col < R_) xb[(size_t)row * 64 + col] = f2b(s);
    }
    for (int i = tid; i < 64 * 16; i += 256) {
      int row = m0 + (i >> 4);
      xb[(size_t)row * 64 + R_ + (i & 15)] = 0;
    }
  }
}

// ---- Parallel (chunked) selective scan --------------------------------------
__global__ __launch_bounds__(256, 6) void k_scanA(const ushort* __restrict__ u, const ushort* __restrict__ dtb,
                                                  const float* __restrict__ xdbc, const float* __restrict__ A_log,
                                                  float* __restrict__ Pst, float* __restrict__ Sst) {
  __shared__ float2 s_dtu[CL_][16];
  __shared__ float  s_b [CL_][16];
  const int tid = threadIdx.x;
  const int e0 = blockIdx.x << 4;
  const int b  = blockIdx.y;
  const int c  = blockIdx.z;
  const int n  = tid & 15, el = tid >> 4;
  const int e  = e0 + el;
  const float A = -__expf(A_log[e * N_ + n]);
  const int t0 = c * CL_;

  ushort r_dt[4], r_u[4];
  float r_b[4];
  #pragma unroll
  for (int j = 0; j < 4; j++) {
    size_t m = (size_t)(b * L_ + t0 + j * 16 + el);
    r_dt[j] = dtb[m * E_ + e0 + n];
    r_u[j]  = u[m * E_ + e0 + n];
    int idx = j * 256 + tid;
    r_b[j] = xdbc[(size_t)(b * L_ + t0 + (idx >> 4)) * XD_ + R_ + (idx & 15)];
  }
  #pragma unroll
  for (int j = 0; j < 4; j++) {
    int t = j * 16 + el;
    float dtv = b2f(r_dt[j]);
    s_dtu[t][n] = make_float2(dtv, dtv * b2f(r_u[j]));
    int idx = j * 256 + tid;
    s_b[idx >> 4][idx & 15] = r_b[j];
  }
  __syncthreads();

  float hs = 0.0f, pp = 1.0f;
  #pragma unroll 8
  for (int t = 0; t < CL_; t++) {
    float2 dtu = s_dtu[t][el];
    float dA = __expf(dtu.x * A);
    hs = fmaf(hs, dA, dtu.y * s_b[t][n]);
    pp *= dA;
  }
  size_t o = (((size_t)(b * NCH_ + c) * E_) + e) * N_ + n;
  Pst[o] = pp;
  Sst[o] = hs;
}

__global__ __launch_bounds__(256, 6) void k_scanC(const ushort* __restrict__ u, const ushort* __restrict__ dtb,
                                                  const float* __restrict__ xdbc, const ushort* __restrict__ gb,
                                                  const float* __restrict__ A_log, const float* __restrict__ Dp,
                                                  const float* __restrict__ Pst, const float* __restrict__ Sst,
                                                  ushort* __restrict__ y) {
  __shared__ float2 s_dtu[CL_][16];
  __shared__ float2 s_bc [CL_][16];
  __shared__ float2 s_og [CL_][16];
  __shared__ ushort s_y [CL_][16];
  const int tid = threadIdx.x;
  const int e0 = blockIdx.x << 4;
  const int b  = blockIdx.y;
  const int c  = blockIdx.z;
  const int n  = tid & 15, el = tid >> 4;
  const int e  = e0 + el;
  const float A = -__expf(A_log[e * N_ + n]);
  const float Dv = Dp[e0 + n];
  const int t0 = c * CL_;

  ushort r_dt[4], r_u[4], r_g[4];
  float r_bc[8];
  #pragma unroll
  for (int j = 0; j < 4; j++) {
    size_t m = (size_t)(b * L_ + t0 + j * 16 + el);
    r_dt[j] = dtb[m * E_ + e0 + n];
    r_u[j]  = u[m * E_ + e0 + n];
    r_g[j]  = gb[m * E_ + e0 + n];
  }
  #pragma unroll
  for (int j = 0; j < 8; j++) {
    int idx = j * 256 + tid;
    r_bc[j] = xdbc[(size_t)(b * L_ + t0 + (idx >> 5)) * XD_ + R_ + (idx & 31)];
  }

  // branchless parallel lookback
  float hs = 0.0f;
  if (c > 0) {
    float pv[NCH_ - 1], sv[NCH_ - 1];
    #pragma unroll
    for (int cc = 0; cc < NCH_ - 1; cc++) {
      int ci = cc < c ? cc : c - 1;
      size_t o = (((size_t)(b * NCH_ + ci) * E_) + e) * N_ + n;
      pv[cc] = Pst[o];
      sv[cc] = Sst[o];
    }
    #pragma unroll
    for (int cc = 0; cc < NCH_ - 1; cc++) {
      bool v = cc < c;
      hs = fmaf(v ? pv[cc] : 1.0f, hs, v ? sv[cc] : 0.0f);
    }
  }

  #pragma unroll
  for (int j = 0; j < 4; j++) {
    int t = j * 16 + el;
    float dtv = b2f(r_dt[j]);
    float uf = b2f(r_u[j]);
    s_dtu[t][n] = make_float2(dtv, dtv * uf);
    s_og[t][n] = make_float2(uf * Dv, b2f(r_g[j]));
  }
  #pragma unroll
  for (int j = 0; j < 8; j++) {
    int idx = j * 256 + tid;
    int t = idx >> 5, col = idx & 31;
    ((float*)&s_bc[t][0])[((col & 15) << 1) + (col >> 4)] = r_bc[j];
  }
  __syncthreads();

  #pragma unroll 8
  for (int t = 0; t < CL_; t++) {
    float2 dtu = s_dtu[t][el];
    float2 bc  = s_bc[t][n];
    float dA = __expf(dtu.x * A);
    hs = fmaf(hs, dA, dtu.y * bc.x);
    float p = row_sum16(hs * bc.y);
    if (n == 0) {
      float2 og = s_og[t][el];
      s_y[t][el] = f2b((p + og.x) * og.y);
    }
  }
  __syncthreads();

  {
    int row = tid >> 2, seg = tid & 3;
    uint2 v = *(const uint2*)&s_y[row][seg * 4];
    *(uint2*)(y + (size_t)(b * L_ + t0 + row) * E_ + e0 + seg * 4) = v;
  }
}

// rs[m] = rsqrt(mean(h[m,:]^2)+eps)
__global__ __launch_bounds__(256) void k_rowscale(const float* __restrict__ h, float* __restrict__ rs) {
  __shared__ float sm[4];
  int m = blockIdx.x, tid = threadIdx.x;
  const float* row = h + (size_t)m * D_;
  float v0 = row[tid], v1 = row[tid + 256], v2 = row[tid + 512];
  float s = block_sum(v0 * v0 + v1 * v1 + v2 * v2, sm);
  if (tid == 0) rs[m] = rsqrtf(s * (1.0f / D_) + EPS_);
}

// pooled[b,d] = fnorm_w[d]/L * sum_t h[b,t,d]*rs[b,t]  (no atomics, no memset)
__global__ __launch_bounds__(256) void k_pool(const float* __restrict__ h, const float* __restrict__ rs,
                                              const float* __restrict__ fw, float* __restrict__ pooled) {
  int d = blockIdx.x * 256 + threadIdx.x;
  int b = blockIdx.y;
  float acc = 0.0f;
  for (int t = 0; t < L_; t++) {
    int m = b * L_ + t;
    acc = fmaf(h[(size_t)m * D_ + d], rs[m], acc);
  }
  pooled[b * D_ + d] = acc * fw[d] * (1.0f / L_);
}

// out[b,c] = pooled[b,:] @ cls_w[c,:] + cls_b[c]
__global__ __launch_bounds__(256) void k_logits(const float* __restrict__ pooled, const float* __restrict__ cw,
                                                const float* __restrict__ cb, float* __restrict__ out) {
  int wv = threadIdx.x >> 6, ln = threadIdx.x & 63;
  for (int p = wv; p < B_ * NC_; p += 4) {
    int b = p / NC_, c = p % NC_;
    float s = 0.0f;
    for (int d = ln; d < D_; d += 64) s = fmaf(pooled[b * D_ + d], cw[c * D_ + d], s);
    #pragma unroll
    for (int o = 32; o > 0; o >>= 1) s += __shfl_xor(s, o);
    if (ln == 0) out[p] = s + cb[c];
  }
}

extern "C" void kernel_launch(void* const* d_in, const int* in_sizes, int n_in,
                              void* d_out, int out_size, void* d_ws, size_t ws_size,
                              hipStream_t stream) {
  const float* x       = (const float*)d_in[0];
  const float* proj_w  = (const float*)d_in[1];
  const float* proj_b  = (const float*)d_in[2];
  const float* norm_w  = (const float*)d_in[3];
  const float* in_w    = (const float*)d_in[4];
  const float* conv_w  = (const float*)d_in[5];
  const float* conv_b  = (const float*)d_in[6];
  const float* xproj_w = (const float*)d_in[7];
  const float* dt_w    = (const float*)d_in[8];
  const float* dt_b    = (const float*)d_in[9];
  const float* A_log   = (const float*)d_in[10];
  const float* D_param = (const float*)d_in[11];
  const float* out_w   = (const float*)d_in[12];
  const float* fnorm_w = (const float*)d_in[13];
  const float* cls_w   = (const float*)d_in[14];
  const float* cls_b   = (const float*)d_in[15];
  float* out = (float*)d_out;

  // workspace layout
  float* h      = (float*)d_ws;                         // M*D
  float* xdbc   = h + (size_t)M_ * D_;                  // M*80
  float* rsb    = xdbc + (size_t)M_ * XD_;              // M
  float* pooled = rsb + M_;                             // B*D
  float* Pst    = pooled + B_ * D_;                     // B*NCH*E*N
  float* Sst    = Pst + (size_t)B_ * NCH_ * E_ * N_;    // B*NCH*E*N
  float* xpart  = Sst + (size_t)B_ * NCH_ * E_ * N_;    // KS*M*80
  int*   cnt    = (int*)(xpart + (size_t)KS_ * M_ * XD_);  // NL*32 counters
  ushort* proju_bf = (ushort*)(cnt + NL_ * NMB_);       // M*E bf16 (u-half of in-proj)
  ushort* g_bf    = proju_bf + (size_t)M_ * E_;         // M*E bf16 silu(gate)
  ushort* hn_bf   = g_bf + (size_t)M_ * E_;             // M*D
  ushort* y_bf    = hn_bf + (size_t)M_ * D_;            // M*E
  ushort* ub_bf   = y_bf + (size_t)M_ * E_;             // M*E
  ushort* dt_bf   = ub_bf + (size_t)M_ * E_;            // M*E
  ushort* xdbc_bf = dt_bf + (size_t)M_ * E_;            // M*64
  ushort* xwb     = xdbc_bf + (size_t)M_ * 64;          // NL*80*E
  ushort* dtwb    = xwb + (size_t)NL_ * XD_ * E_;       // NL*E*64
  ushort* in_wb   = dtwb + (size_t)NL_ * E_ * 64;       // NL*E2*D
  ushort* out_wb  = in_wb + (size_t)NL_ * E2_ * D_;     // NL*D*E

  constexpr int WTOT = WS1_ + WS2_ + WS3_ + WS4_;
  k_wprep<<<(WTOT / 4 + 255) / 256, 256, 0, stream>>>(in_w, out_w, xproj_w, dt_w,
                                                      in_wb, out_wb, xwb, dtwb, cnt);

  k_proj<<<dim3(D_ / 256, M_), 256, 0, stream>>>(x, proj_w, proj_b, h);

  for (int i = 0; i < NL_; i++) {
    k_rmsnorm_bf<<<M_, 256, 0, stream>>>(h, norm_w + i * D_, hn_bf);
    k_gemm_bf<128, 128, 4><<<dim3(E2_ / 128, M_ / 128), 256, 0, stream>>>(
        hn_bf, in_wb + (size_t)i * E2_ * D_, proju_bf, nullptr, g_bf, D_, E2_);
    k_gemm_xc<<<dim3(M_ / 64, KS_), 256, 0, stream>>>(proju_bf, conv_w + i * E_ * 4, conv_b + i * E_,
                                                      xwb + (size_t)i * XD_ * E_, ub_bf, xpart,
                                                      cnt + i * NMB_, xdbc, xdbc_bf);
    k_gemm_bf<64, 64, 6><<<dim3(E_ / 64, M_ / 64), 256, 0, stream>>>(
        xdbc_bf, dtwb + (size_t)i * E_ * 64, dt_bf, dt_b + i * E_, nullptr, 64, E_);
    k_scanA<<<dim3(E_ / 16, B_, NCH_), 256, 0, stream>>>(ub_bf, dt_bf, xdbc,
                                                         A_log + (size_t)i * E_ * N_, Pst, Sst);
    k_scanC<<<dim3(E_ / 16, B_, NCH_), 256, 0, stream>>>(ub_bf, dt_bf, xdbc, g_bf,
                                                         A_log + (size_t)i * E_ * N_, D_param + i * E_,
                                                         Pst, Sst, y_bf);
    k_gemm_bf<64, 64, 1><<<dim3(D_ / 64, M_ / 64), 256, 0, stream>>>(
        y_bf, out_wb + (size_t)i * D_ * E_, h, h, nullptr, E_, D_);
  }

  k_rowscale<<<M_, 256, 0, stream>>>(h, rsb);
  k_pool<<<dim3(D_ / 256, B_), 256, 0, stream>>>(h, rsb, fnorm_w, pooled);
  k_logits<<<1, 256, 0, stream>>>(pooled, cls_w, cls_b, out);
}

// Round 10
// 732.515 us; speedup vs baseline: 1.1561x; 1.1561x over previous
//
#include <hip/hip_runtime.h>

// Problem constants (match reference)
constexpr int B_  = 2;
constexpr int L_  = 1024;
constexpr int D_  = 768;
constexpr int E_  = 1536;
constexpr int N_  = 16;
constexpr int R_  = 48;
constexpr int NL_ = 4;
constexpr int NC_ = 5;
constexpr int M_  = B_ * L_;        // 2048 token rows
constexpr int E2_ = 2 * E_;         // 3072
constexpr int XD_ = R_ + 2 * N_;    // 80
constexpr float EPS_ = 1e-5f;

constexpr int NCH_ = 16;            // time-chunks for parallel scan
constexpr int CL_  = L_ / NCH_;     // 64 timesteps per chunk
constexpr int KS_  = 8;             // split-K factor for xproj GEMM
constexpr int PC_  = 8;             // t-chunks for final pool

typedef __attribute__((ext_vector_type(8))) short bf16x8;
typedef __attribute__((ext_vector_type(4))) float f32x4;
typedef const __attribute__((address_space(1))) void* gas_t;
typedef __attribute__((address_space(3))) void* las_t;

__device__ __forceinline__ float sigm(float x) { return 1.0f / (1.0f + __expf(-x)); }
__device__ __forceinline__ float softplusf(float x) { return x > 20.0f ? x : log1pf(__expf(x)); }
__device__ __forceinline__ ushort f2b(float f) {  // fp32 -> bf16 RNE
  union { float f; unsigned u; } v; v.f = f;
  unsigned r = (v.u + 0x7fffu + ((v.u >> 16) & 1u)) >> 16;
  return (ushort)r;
}
__device__ __forceinline__ float b2f(ushort u) {
  union { unsigned u; float f; } v; v.u = ((unsigned)u) << 16;
  return v.f;
}
__device__ __forceinline__ float b2f_lo(unsigned p) {
  union { unsigned u; float f; } v; v.u = p << 16;
  return v.f;
}
__device__ __forceinline__ float b2f_hi(unsigned p) {
  union { unsigned u; float f; } v; v.u = p & 0xffff0000u;
  return v.f;
}

// DPP row_ror add: sum over 16-lane rows, full-rate VALU
template <int CTRL>
__device__ __forceinline__ float dpp_add(float x) {
  int yi = __builtin_amdgcn_update_dpp(0, __builtin_bit_cast(int, x), CTRL, 0xf, 0xf, false);
  return x + __builtin_bit_cast(float, yi);
}
__device__ __forceinline__ float row_sum16(float x) {
  x = dpp_add<0x121>(x);
  x = dpp_add<0x122>(x);
  x = dpp_add<0x124>(x);
  x = dpp_add<0x128>(x);
  return x;
}

__device__ __forceinline__ float block_sum(float v, float* sm) {
  #pragma unroll
  for (int o = 32; o > 0; o >>= 1) v += __shfl_xor(v, o);
  if ((threadIdx.x & 63) == 0) sm[threadIdx.x >> 6] = v;
  __syncthreads();
  return sm[0] + sm[1] + sm[2] + sm[3];
}

// One-shot weight prep: in_w, out_w, xproj_w plain f2b; dt_w padded 48->64
constexpr int WS1_ = NL_ * E2_ * D_;
constexpr int WS2_ = NL_ * D_ * E_;
constexpr int WS3_ = NL_ * XD_ * E_;
constexpr int WS4_ = NL_ * E_ * 64;
__global__ __launch_bounds__(256) void k_wprep(const float* __restrict__ in_w, const float* __restrict__ out_w,
                                               const float* __restrict__ xw, const float* __restrict__ dw,
                                               ushort* __restrict__ in_wb, ushort* __restrict__ out_wb,
                                               ushort* __restrict__ xwb, ushort* __restrict__ dtwb) {
  int i = (blockIdx.x * 256 + threadIdx.x) * 4;
  if (i < WS1_) {
    float4 v = *(const float4*)(in_w + i);
    *(ushort4*)(in_wb + i) = make_ushort4(f2b(v.x), f2b(v.y), f2b(v.z), f2b(v.w));
  } else if (i < WS1_ + WS2_) {
    int j = i - WS1_;
    float4 v = *(const float4*)(out_w + j);
    *(ushort4*)(out_wb + j) = make_ushort4(f2b(v.x), f2b(v.y), f2b(v.z), f2b(v.w));
  } else if (i < WS1_ + WS2_ + WS3_) {
    int j = i - WS1_ - WS2_;
    float4 v = *(const float4*)(xw + j);
    *(ushort4*)(xwb + j) = make_ushort4(f2b(v.x), f2b(v.y), f2b(v.z), f2b(v.w));
  } else if (i < WS1_ + WS2_ + WS3_ + WS4_) {
    int j = i - WS1_ - WS2_ - WS3_;
    int k = j & 63, e = j >> 6;
    ushort4 o;
    o.x = (k + 0 < R_) ? f2b(dw[e * R_ + k + 0]) : (ushort)0;
    o.y = (k + 1 < R_) ? f2b(dw[e * R_ + k + 1]) : (ushort)0;
    o.z = (k + 2 < R_) ? f2b(dw[e * R_ + k + 2]) : (ushort)0;
    o.w = (k + 3 < R_) ? f2b(dw[e * R_ + k + 3]) : (ushort)0;
    *(ushort4*)(dtwb + j) = o;
  }
}

// h[m,d] = x[m,:12] @ proj_w[d,:12] + proj_b[d]
__global__ __launch_bounds__(256) void k_proj(const float* __restrict__ x, const float* __restrict__ pw,
                                              const float* __restrict__ pb, float* __restrict__ h) {
  __shared__ float xs[12];
  int m = blockIdx.y;
  int d = blockIdx.x * 256 + threadIdx.x;
  if (threadIdx.x < 12) xs[threadIdx.x] = x[m * 12 + threadIdx.x];
  __syncthreads();
  float acc = pb[d];
  #pragma unroll
  for (int j = 0; j < 12; j++) acc = fmaf(xs[j], pw[d * 12 + j], acc);
  h[(size_t)m * D_ + d] = acc;
}

// hn_bf16[m,:] = rmsnorm(h[m,:]) * w
__global__ __launch_bounds__(256) void k_rmsnorm_bf(const float* __restrict__ h, const float* __restrict__ w,
                                                    ushort* __restrict__ hn) {
  __shared__ float sm[4];
  int m = blockIdx.x, tid = threadIdx.x;
  const float* row = h + (size_t)m * D_;
  float v0 = row[tid], v1 = row[tid + 256], v2 = row[tid + 512];
  float s = block_sum(v0 * v0 + v1 * v1 + v2 * v2, sm);
  float sc = rsqrtf(s * (1.0f / D_) + EPS_);
  ushort* o = hn + (size_t)m * D_;
  o[tid]       = f2b(v0 * sc * w[tid]);
  o[tid + 256] = f2b(v1 * sc * w[tid + 256]);
  o[tid + 512] = f2b(v2 * sc * w[tid + 512]);
}

// C[M,Nd] = A_bf16[M,Kd] @ Bw_bf16[Nd,Kd]^T. MFMA 16x16x32 bf16.
// MODE 0: fp32 C=v  MODE 1: fp32 C=v+res[off]  MODE 2: fp32 C=softplus(v+res[col])
// MODE 3: bf16 C=v
template <int BM, int BN, int MODE>
__global__ __launch_bounds__(256) void k_gemm_bf(const ushort* __restrict__ A, const ushort* __restrict__ Bw,
                                                 void* __restrict__ Cv, const float* __restrict__ res,
                                                 int Kd, int Nd) {
  constexpr int AM = BM / 32, BNF = BN / 32;
  __shared__ ushort sA[BM * 32];
  __shared__ ushort sB[BN * 32];
  const int tid = threadIdx.x;
  const int wave = tid >> 6, lane = tid & 63;
  const int q = lane >> 4, r = lane & 15;
  const int wm = wave >> 1, wn = wave & 1;
  const int m0 = blockIdx.y * BM, n0 = blockIdx.x * BN;
  f32x4 acc[AM][BNF] = {};

  for (int k0 = 0; k0 < Kd; k0 += 32) {
    #pragma unroll
    for (int j = 0; j < BM / 64; j++) {
      int i = j * 256 + tid;
      const ushort* gp = A + (size_t)(m0 + (i >> 2)) * Kd + k0 + ((i & 3) << 3);
      __builtin_amdgcn_global_load_lds((gas_t)gp, (las_t)(sA + ((j * 256 + wave * 64) << 3)), 16, 0, 0);
    }
    #pragma unroll
    for (int j = 0; j < BN / 64; j++) {
      int i = j * 256 + tid;
      const ushort* gp = Bw + (size_t)(n0 + (i >> 2)) * Kd + k0 + ((i & 3) << 3);
      __builtin_amdgcn_global_load_lds((gas_t)gp, (las_t)(sB + ((j * 256 + wave * 64) << 3)), 16, 0, 0);
    }
    __syncthreads();
    bf16x8 af[AM], bfv[BNF];
    #pragma unroll
    for (int mi = 0; mi < AM; mi++)
      af[mi] = *(const bf16x8*)&sA[(wm * (BM / 2) + mi * 16 + r) * 32 + q * 8];
    #pragma unroll
    for (int nj = 0; nj < BNF; nj++)
      bfv[nj] = *(const bf16x8*)&sB[(wn * (BN / 2) + nj * 16 + r) * 32 + q * 8];
    #pragma unroll
    for (int mi = 0; mi < AM; mi++)
      #pragma unroll
      for (int nj = 0; nj < BNF; nj++)
        acc[mi][nj] = __builtin_amdgcn_mfma_f32_16x16x32_bf16(af[mi], bfv[nj], acc[mi][nj], 0, 0, 0);
    __syncthreads();
  }
  // C/D layout: col = lane&15, row = (lane>>4)*4 + reg
  #pragma unroll
  for (int mi = 0; mi < AM; mi++) {
    #pragma unroll
    for (int nj = 0; nj < BNF; nj++) {
      int col = n0 + wn * (BN / 2) + nj * 16 + r;
      #pragma unroll
      for (int rg = 0; rg < 4; rg++) {
        int row = m0 + wm * (BM / 2) + mi * 16 + q * 4 + rg;
        size_t off = (size_t)row * Nd + col;
        float v = acc[mi][nj][rg];
        if (MODE == 3) {
          ((ushort*)Cv)[off] = f2b(v);
        } else {
          if (MODE == 1) v += res[off];
          if (MODE == 2) v = softplusf(v + res[col]);
          ((float*)Cv)[off] = v;
        }
      }
    }
  }
}

// xproj GEMM, split-K: part[ks][M][80] = u_bf[M, ks-slice] @ xwb[80, ks-slice]^T
__global__ __launch_bounds__(256) void k_gemm_x(const ushort* __restrict__ A, const ushort* __restrict__ Bw,
                                                float* __restrict__ part) {
  __shared__ ushort sA[64 * 32];
  __shared__ ushort sB[80 * 32];
  const int tid = threadIdx.x;
  const int wave = tid >> 6, lane = tid & 63;
  const int q = lane >> 4, r = lane & 15;
  const int m0 = blockIdx.x * 64;
  const int kbeg = blockIdx.y * (E_ / KS_), kend = kbeg + E_ / KS_;
  f32x4 acc[5] = {};

  for (int k0 = kbeg; k0 < kend; k0 += 32) {
    {
      const ushort* gp = A + (size_t)(m0 + wave * 16 + (lane >> 2)) * E_ + k0 + ((lane & 3) << 3);
      __builtin_amdgcn_global_load_lds((gas_t)gp, (las_t)(sA + (wave << 9)), 16, 0, 0);
    }
    #pragma unroll
    for (int j = wave; j < 5; j += 4) {
      const ushort* gp = Bw + (size_t)(j * 16 + (lane >> 2)) * E_ + k0 + ((lane & 3) << 3);
      __builtin_amdgcn_global_load_lds((gas_t)gp, (las_t)(sB + (j << 9)), 16, 0, 0);
    }
    __syncthreads();
    bf16x8 af = *(const bf16x8*)&sA[(wave * 16 + r) * 32 + q * 8];
    #pragma unroll
    for (int nj = 0; nj < 5; nj++) {
      bf16x8 bfv = *(const bf16x8*)&sB[(nj * 16 + r) * 32 + q * 8];
      acc[nj] = __builtin_amdgcn_mfma_f32_16x16x32_bf16(af, bfv, acc[nj], 0, 0, 0);
    }
    __syncthreads();
  }
  float* pp = part + (size_t)blockIdx.y * M_ * XD_;
  #pragma unroll
  for (int nj = 0; nj < 5; nj++) {
    int col = nj * 16 + r;
    #pragma unroll
    for (int rg = 0; rg < 4; rg++) {
      int row = m0 + wave * 16 + q * 4 + rg;
      pp[(size_t)row * XD_ + col] = acc[nj][rg];
    }
  }
}

// combine split-K partials -> xdbc fp32 [M][80] + bf16 dt-input copy [M][64]
__global__ __launch_bounds__(256) void k_xfin(const float* __restrict__ part, float* __restrict__ xdbc,
                                              ushort* __restrict__ xb) {
  int i = blockIdx.x * 256 + threadIdx.x;   // over M*80
  int m = i / XD_, col = i - m * XD_;
  float s = 0.0f;
  #pragma unroll
  for (int ks = 0; ks < KS_; ks++) s += part[(size_t)ks * M_ * XD_ + i];
  xdbc[i] = s;
  if (col < R_) xb[(size_t)m * 64 + col] = f2b(s);
  else if (col < 64) xb[(size_t)m * 64 + col] = 0;
}

// conv + silu for u; silu for gate. bf16 in (proj_bf), bf16 out. 4 e / thread.
__global__ __launch_bounds__(384) void k_conv2(const ushort* __restrict__ proj, const float* __restrict__ cw,
                                               const float* __restrict__ cb, ushort* __restrict__ ub16,
                                               ushort* __restrict__ gb16) {
  int m = blockIdx.x;
  int b = m >> 10, t = m & (L_ - 1);
  int e4 = threadIdx.x * 4;
  float wv[4][4];
  #pragma unroll
  for (int j = 0; j < 4; j++) {
    float4 w = *(const float4*)(cw + (e4 + j) * 4);
    wv[j][0] = w.x; wv[j][1] = w.y; wv[j][2] = w.z; wv[j][3] = w.w;
  }
  float4 bb = *(const float4*)(cb + e4);
  float acc[4] = {bb.x, bb.y, bb.z, bb.w};
  #pragma unroll
  for (int k = 0; k < 4; k++) {
    int tt = t + k - 3;
    if (tt >= 0) {
      uint2 p = *(const uint2*)(proj + (size_t)(b * L_ + tt) * E2_ + e4);
      acc[0] = fmaf(wv[0][k], b2f_lo(p.x), acc[0]);
      acc[1] = fmaf(wv[1][k], b2f_hi(p.x), acc[1]);
      acc[2] = fmaf(wv[2][k], b2f_lo(p.y), acc[2]);
      acc[3] = fmaf(wv[3][k], b2f_hi(p.y), acc[3]);
    }
  }
  uint2 uo;
  {
    float u0 = acc[0] * sigm(acc[0]), u1 = acc[1] * sigm(acc[1]);
    float u2 = acc[2] * sigm(acc[2]), u3 = acc[3] * sigm(acc[3]);
    uo.x = (unsigned)f2b(u0) | ((unsigned)f2b(u1) << 16);
    uo.y = (unsigned)f2b(u2) | ((unsigned)f2b(u3) << 16);
  }
  *(uint2*)(ub16 + (size_t)m * E_ + e4) = uo;
  // gate -> silu -> bf16
  uint2 g = *(const uint2*)(proj + (size_t)m * E2_ + E_ + e4);
  float g0 = b2f_lo(g.x), g1 = b2f_hi(g.x), g2 = b2f_lo(g.y), g3 = b2f_hi(g.y);
  g0 *= sigm(g0); g1 *= sigm(g1); g2 *= sigm(g2); g3 *= sigm(g3);
  uint2 go;
  go.x = (unsigned)f2b(g0) | ((unsigned)f2b(g1) << 16);
  go.y = (unsigned)f2b(g2) | ((unsigned)f2b(g3) << 16);
  *(uint2*)(gb16 + (size_t)m * E_ + e4) = go;
}

// ---- Parallel (chunked) selective scan, single-shot chunk staging -----------
__global__ __launch_bounds__(256, 6) void k_scanA(const ushort* __restrict__ u, const float* __restrict__ dtb,
                                                  const float* __restrict__ xdbc, const float* __restrict__ A_log,
                                                  float* __restrict__ Pst, float* __restrict__ Sst) {
  __shared__ float2 s_dtu[CL_][16];
  __shared__ float  s_b [CL_][16];
  const int tid = threadIdx.x;
  const int e0 = blockIdx.x << 4;
  const int b  = blockIdx.y;
  const int c  = blockIdx.z;
  const int n  = tid & 15, el = tid >> 4;
  const int e  = e0 + el;
  const float A = -__expf(A_log[e * N_ + n]);
  const int t0 = c * CL_;

  float r_dt[4], r_b[4];
  ushort r_u[4];
  #pragma unroll
  for (int j = 0; j < 4; j++) {
    size_t m = (size_t)(b * L_ + t0 + j * 16 + el);
    r_dt[j] = dtb[m * E_ + e0 + n];
    r_u[j]  = u[m * E_ + e0 + n];
    int idx = j * 256 + tid;
    r_b[j] = xdbc[(size_t)(b * L_ + t0 + (idx >> 4)) * XD_ + R_ + (idx & 15)];
  }
  #pragma unroll
  for (int j = 0; j < 4; j++) {
    int t = j * 16 + el;
    s_dtu[t][n] = make_float2(r_dt[j], r_dt[j] * b2f(r_u[j]));
    int idx = j * 256 + tid;
    s_b[idx >> 4][idx & 15] = r_b[j];
  }
  __syncthreads();

  float hs = 0.0f, pp = 1.0f;
  #pragma unroll 8
  for (int t = 0; t < CL_; t++) {
    float2 dtu = s_dtu[t][el];
    float dA = __expf(dtu.x * A);
    hs = fmaf(hs, dA, dtu.y * s_b[t][n]);
    pp *= dA;
  }
  size_t o = (((size_t)(b * NCH_ + c) * E_) + e) * N_ + n;
  Pst[o] = pp;
  Sst[o] = hs;
}

__global__ __launch_bounds__(256, 6) void k_scanC(const ushort* __restrict__ u, const float* __restrict__ dtb,
                                                  const float* __restrict__ xdbc, const ushort* __restrict__ gb,
                                                  const float* __restrict__ A_log, const float* __restrict__ Dp,
                                                  const float* __restrict__ Pst, const float* __restrict__ Sst,
                                                  ushort* __restrict__ y) {
  __shared__ float2 s_dtu[CL_][16];
  __shared__ float2 s_bc [CL_][16];
  __shared__ float2 s_og [CL_][16];
  __shared__ ushort s_y [CL_][16];
  const int tid = threadIdx.x;
  const int e0 = blockIdx.x << 4;
  const int b  = blockIdx.y;
  const int c  = blockIdx.z;
  const int n  = tid & 15, el = tid >> 4;
  const int e  = e0 + el;
  const float A = -__expf(A_log[e * N_ + n]);
  const float Dv = Dp[e0 + n];
  const int t0 = c * CL_;

  float r_dt[4], r_bc[8];
  ushort r_u[4], r_g[4];
  #pragma unroll
  for (int j = 0; j < 4; j++) {
    size_t m = (size_t)(b * L_ + t0 + j * 16 + el);
    r_dt[j] = dtb[m * E_ + e0 + n];
    r_u[j]  = u[m * E_ + e0 + n];
    r_g[j]  = gb[m * E_ + e0 + n];
  }
  #pragma unroll
  for (int j = 0; j < 8; j++) {
    int idx = j * 256 + tid;
    r_bc[j] = xdbc[(size_t)(b * L_ + t0 + (idx >> 5)) * XD_ + R_ + (idx & 31)];
  }

  // branchless parallel lookback over predecessor chunk summaries
  float hs = 0.0f;
  if (c > 0) {
    float pv[NCH_ - 1], sv[NCH_ - 1];
    #pragma unroll
    for (int cc = 0; cc < NCH_ - 1; cc++) {
      int ci = cc < c ? cc : c - 1;
      size_t o = (((size_t)(b * NCH_ + ci) * E_) + e) * N_ + n;
      pv[cc] = Pst[o];
      sv[cc] = Sst[o];
    }
    #pragma unroll
    for (int cc = 0; cc < NCH_ - 1; cc++) {
      bool v = cc < c;
      hs = fmaf(v ? pv[cc] : 1.0f, hs, v ? sv[cc] : 0.0f);
    }
  }

  #pragma unroll
  for (int j = 0; j < 4; j++) {
    int t = j * 16 + el;
    float uf = b2f(r_u[j]);
    s_dtu[t][n] = make_float2(r_dt[j], r_dt[j] * uf);
    s_og[t][n] = make_float2(uf * Dv, b2f(r_g[j]));
  }
  #pragma unroll
  for (int j = 0; j < 8; j++) {
    int idx = j * 256 + tid;
    int t = idx >> 5, col = idx & 31;
    ((float*)&s_bc[t][0])[((col & 15) << 1) + (col >> 4)] = r_bc[j];
  }
  __syncthreads();

  #pragma unroll 8
  for (int t = 0; t < CL_; t++) {
    float2 dtu = s_dtu[t][el];
    float2 bc  = s_bc[t][n];
    float dA = __expf(dtu.x * A);
    hs = fmaf(hs, dA, dtu.y * bc.x);
    float p = row_sum16(hs * bc.y);
    if (n == 0) {
      float2 og = s_og[t][el];
      s_y[t][el] = f2b((p + og.x) * og.y);
    }
  }
  __syncthreads();

  {
    int row = tid >> 2, seg = tid & 3;
    uint2 v = *(const uint2*)&s_y[row][seg * 4];
    *(uint2*)(y + (size_t)(b * L_ + t0 + row) * E_ + e0 + seg * 4) = v;
  }
}

// rs[m] = rsqrt(mean(h[m,:]^2)+eps)
__global__ __launch_bounds__(256) void k_rowscale(const float* __restrict__ h, float* __restrict__ rs) {
  __shared__ float sm[4];
  int m = blockIdx.x, tid = threadIdx.x;
  const float* row = h + (size_t)m * D_;
  float v0 = row[tid], v1 = row[tid + 256], v2 = row[tid + 512];
  float s = block_sum(v0 * v0 + v1 * v1 + v2 * v2, sm);
  if (tid == 0) rs[m] = rsqrtf(s * (1.0f / D_) + EPS_);
}

// partial pool: pooledP[pc][b][d] = sum over the pc-th t-chunk of h*rs (no atomics/memset)
__global__ __launch_bounds__(256) void k_pool(const float* __restrict__ h, const float* __restrict__ rs,
                                              float* __restrict__ pooledP) {
  int d = blockIdx.x * 256 + threadIdx.x;
  int pc = blockIdx.y;
  int b = blockIdx.z;
  int t0 = pc * (L_ / PC_);
  float acc = 0.0f;
  for (int t = t0; t < t0 + L_ / PC_; t++) {
    int m = b * L_ + t;
    acc = fmaf(h[(size_t)m * D_ + d], rs[m], acc);
  }
  pooledP[((size_t)pc * B_ + b) * D_ + d] = acc;
}

// out[b,c] = (fw/L * sum_pc pooledP) @ cls_w[c,:] + cls_b[c]
__global__ __launch_bounds__(256) void k_logits(const float* __restrict__ pooledP, const float* __restrict__ fw,
                                                const float* __restrict__ cw, const float* __restrict__ cb,
                                                float* __restrict__ out) {
  int wv = threadIdx.x >> 6, ln = threadIdx.x & 63;
  for (int p = wv; p < B_ * NC_; p += 4) {
    int b = p / NC_, c = p % NC_;
    float s = 0.0f;
    for (int d = ln; d < D_; d += 64) {
      float pd = 0.0f;
      #pragma unroll
      for (int pc = 0; pc < PC_; pc++) pd += pooledP[((size_t)pc * B_ + b) * D_ + d];
      s = fmaf(pd * fw[d], cw[c * D_ + d], s);
    }
    #pragma unroll
    for (int o = 32; o > 0; o >>= 1) s += __shfl_xor(s, o);
    if (ln == 0) out[p] = s * (1.0f / L_) + cb[c];
  }
}

extern "C" void kernel_launch(void* const* d_in, const int* in_sizes, int n_in,
                              void* d_out, int out_size, void* d_ws, size_t ws_size,
                              hipStream_t stream) {
  const float* x       = (const float*)d_in[0];
  const float* proj_w  = (const float*)d_in[1];
  const float* proj_b  = (const float*)d_in[2];
  const float* norm_w  = (const float*)d_in[3];
  const float* in_w    = (const float*)d_in[4];
  const float* conv_w  = (const float*)d_in[5];
  const float* conv_b  = (const float*)d_in[6];
  const float* xproj_w = (const float*)d_in[7];
  const float* dt_w    = (const float*)d_in[8];
  const float* dt_b    = (const float*)d_in[9];
  const float* A_log   = (const float*)d_in[10];
  const float* D_param = (const float*)d_in[11];
  const float* out_w   = (const float*)d_in[12];
  const float* fnorm_w = (const float*)d_in[13];
  const float* cls_w   = (const float*)d_in[14];
  const float* cls_b   = (const float*)d_in[15];
  float* out = (float*)d_out;

  // workspace layout
  float* h      = (float*)d_ws;                         // M*D
  float* xdbc   = h + (size_t)M_ * D_;                  // M*80
  float* dtbuf  = xdbc + (size_t)M_ * XD_;              // M*E fp32 dt
  float* rsb    = dtbuf + (size_t)M_ * E_;              // M
  float* pooledP = rsb + M_;                            // PC*B*D
  float* Pst    = pooledP + (size_t)PC_ * B_ * D_;      // B*NCH*E*N
  float* Sst    = Pst + (size_t)B_ * NCH_ * E_ * N_;    // B*NCH*E*N
  float* xpart  = Sst + (size_t)B_ * NCH_ * E_ * N_;    // KS*M*80
  ushort* proj_bf = (ushort*)(xpart + (size_t)KS_ * M_ * XD_);  // M*2E bf16
  ushort* hn_bf   = proj_bf + (size_t)M_ * E2_;         // M*D
  ushort* y_bf    = hn_bf + (size_t)M_ * D_;            // M*E
  ushort* ub_bf   = y_bf + (size_t)M_ * E_;             // M*E
  ushort* g_bf    = ub_bf + (size_t)M_ * E_;            // M*E
  ushort* xdbc_bf = g_bf + (size_t)M_ * E_;             // M*64
  ushort* xwb     = xdbc_bf + (size_t)M_ * 64;          // NL*80*E
  ushort* dtwb    = xwb + (size_t)NL_ * XD_ * E_;       // NL*E*64
  ushort* in_wb   = dtwb + (size_t)NL_ * E_ * 64;       // NL*E2*D
  ushort* out_wb  = in_wb + (size_t)NL_ * E2_ * D_;     // NL*D*E

  constexpr int WTOT = WS1_ + WS2_ + WS3_ + WS4_;
  k_wprep<<<(WTOT / 4 + 255) / 256, 256, 0, stream>>>(in_w, out_w, xproj_w, dt_w,
                                                      in_wb, out_wb, xwb, dtwb);

  k_proj<<<dim3(D_ / 256, M_), 256, 0, stream>>>(x, proj_w, proj_b, h);

  for (int i = 0; i < NL_; i++) {
    k_rmsnorm_bf<<<M_, 256, 0, stream>>>(h, norm_w + i * D_, hn_bf);
    k_gemm_bf<64, 128, 3><<<dim3(E2_ / 128, M_ / 64), 256, 0, stream>>>(
        hn_bf, in_wb + (size_t)i * E2_ * D_, proj_bf, nullptr, D_, E2_);
    k_conv2<<<M_, 384, 0, stream>>>(proj_bf, conv_w + i * E_ * 4, conv_b + i * E_, ub_bf, g_bf);
    k_gemm_x<<<dim3(M_ / 64, KS_), 256, 0, stream>>>(ub_bf, xwb + (size_t)i * XD_ * E_, xpart);
    k_xfin<<<M_ * XD_ / 256, 256, 0, stream>>>(xpart, xdbc, xdbc_bf);
    k_gemm_bf<64, 64, 2><<<dim3(E_ / 64, M_ / 64), 256, 0, stream>>>(
        xdbc_bf, dtwb + (size_t)i * E_ * 64, dtbuf, dt_b + i * E_, 64, E_);
    k_scanA<<<dim3(E_ / 16, B_, NCH_), 256, 0, stream>>>(ub_bf, dtbuf, xdbc,
                                                         A_log + (size_t)i * E_ * N_, Pst, Sst);
    k_scanC<<<dim3(E_ / 16, B_, NCH_), 256, 0, stream>>>(ub_bf, dtbuf, xdbc, g_bf,
                                                         A_log + (size_t)i * E_ * N_, D_param + i * E_,
                                                         Pst, Sst, y_bf);
    k_gemm_bf<64, 64, 1><<<dim3(D_ / 64, M_ / 64), 256, 0, stream>>>(
        y_bf, out_wb + (size_t)i * D_ * E_, h, h, E_, D_);
  }

  k_rowscale<<<M_, 256, 0, stream>>>(h, rsb);
  k_pool<<<dim3(D_ / 256, PC_, B_), 256, 0, stream>>>(h, rsb, pooledP);
  k_logits<<<1, 256, 0, stream>>>(pooledP, fnorm_w, cls_w, cls_b, out);
}

// Round 11
// 684.056 us; speedup vs baseline: 1.2380x; 1.0708x over previous
//
#include <hip/hip_runtime.h>

// Problem constants (match reference)
constexpr int B_  = 2;
constexpr int L_  = 1024;
constexpr int D_  = 768;
constexpr int E_  = 1536;
constexpr int N_  = 16;
constexpr int R_  = 48;
constexpr int NL_ = 4;
constexpr int NC_ = 5;
constexpr int M_  = B_ * L_;        // 2048 token rows
constexpr int E2_ = 2 * E_;         // 3072
constexpr int XD_ = R_ + 2 * N_;    // 80
constexpr float EPS_ = 1e-5f;

constexpr int NCH_ = 16;            // time-chunks for parallel scan
constexpr int CL_  = L_ / NCH_;     // 64 timesteps per chunk
constexpr int KS_  = 8;             // split-K factor for xproj GEMM
constexpr int PC_  = 8;             // t-chunks for final pool

typedef __attribute__((ext_vector_type(8))) short bf16x8;
typedef __attribute__((ext_vector_type(4))) float f32x4;
typedef const __attribute__((address_space(1))) void* gas_t;
typedef __attribute__((address_space(3))) void* las_t;

__device__ __forceinline__ float sigm(float x) { return 1.0f / (1.0f + __expf(-x)); }
__device__ __forceinline__ float softplusf(float x) { return x > 20.0f ? x : log1pf(__expf(x)); }
__device__ __forceinline__ ushort f2b(float f) {  // fp32 -> bf16 RNE
  union { float f; unsigned u; } v; v.f = f;
  unsigned r = (v.u + 0x7fffu + ((v.u >> 16) & 1u)) >> 16;
  return (ushort)r;
}
__device__ __forceinline__ float b2f(ushort u) {
  union { unsigned u; float f; } v; v.u = ((unsigned)u) << 16;
  return v.f;
}
__device__ __forceinline__ float b2f_lo(unsigned p) {
  union { unsigned u; float f; } v; v.u = p << 16;
  return v.f;
}
__device__ __forceinline__ float b2f_hi(unsigned p) {
  union { unsigned u; float f; } v; v.u = p & 0xffff0000u;
  return v.f;
}

// DPP row_ror add: sum over 16-lane rows, full-rate VALU
template <int CTRL>
__device__ __forceinline__ float dpp_add(float x) {
  int yi = __builtin_amdgcn_update_dpp(0, __builtin_bit_cast(int, x), CTRL, 0xf, 0xf, false);
  return x + __builtin_bit_cast(float, yi);
}
__device__ __forceinline__ float row_sum16(float x) {
  x = dpp_add<0x121>(x);
  x = dpp_add<0x122>(x);
  x = dpp_add<0x124>(x);
  x = dpp_add<0x128>(x);
  return x;
}

__device__ __forceinline__ float block_sum(float v, float* sm) {
  #pragma unroll
  for (int o = 32; o > 0; o >>= 1) v += __shfl_xor(v, o);
  if ((threadIdx.x & 63) == 0) sm[threadIdx.x >> 6] = v;
  __syncthreads();
  return sm[0] + sm[1] + sm[2] + sm[3];
}

// One-shot weight prep: in_w, out_w, xproj_w plain f2b; dt_w padded 48->64
constexpr int WS1_ = NL_ * E2_ * D_;
constexpr int WS2_ = NL_ * D_ * E_;
constexpr int WS3_ = NL_ * XD_ * E_;
constexpr int WS4_ = NL_ * E_ * 64;
__global__ __launch_bounds__(256) void k_wprep(const float* __restrict__ in_w, const float* __restrict__ out_w,
                                               const float* __restrict__ xw, const float* __restrict__ dw,
                                               ushort* __restrict__ in_wb, ushort* __restrict__ out_wb,
                                               ushort* __restrict__ xwb, ushort* __restrict__ dtwb) {
  int i = (blockIdx.x * 256 + threadIdx.x) * 4;
  if (i < WS1_) {
    float4 v = *(const float4*)(in_w + i);
    *(ushort4*)(in_wb + i) = make_ushort4(f2b(v.x), f2b(v.y), f2b(v.z), f2b(v.w));
  } else if (i < WS1_ + WS2_) {
    int j = i - WS1_;
    float4 v = *(const float4*)(out_w + j);
    *(ushort4*)(out_wb + j) = make_ushort4(f2b(v.x), f2b(v.y), f2b(v.z), f2b(v.w));
  } else if (i < WS1_ + WS2_ + WS3_) {
    int j = i - WS1_ - WS2_;
    float4 v = *(const float4*)(xw + j);
    *(ushort4*)(xwb + j) = make_ushort4(f2b(v.x), f2b(v.y), f2b(v.z), f2b(v.w));
  } else if (i < WS1_ + WS2_ + WS3_ + WS4_) {
    int j = i - WS1_ - WS2_ - WS3_;
    int k = j & 63, e = j >> 6;
    ushort4 o;
    o.x = (k + 0 < R_) ? f2b(dw[e * R_ + k + 0]) : (ushort)0;
    o.y = (k + 1 < R_) ? f2b(dw[e * R_ + k + 1]) : (ushort)0;
    o.z = (k + 2 < R_) ? f2b(dw[e * R_ + k + 2]) : (ushort)0;
    o.w = (k + 3 < R_) ? f2b(dw[e * R_ + k + 3]) : (ushort)0;
    *(ushort4*)(dtwb + j) = o;
  }
}

// h[m,d] = x[m,:12] @ proj_w[d,:12] + proj_b[d]
__global__ __launch_bounds__(256) void k_proj(const float* __restrict__ x, const float* __restrict__ pw,
                                              const float* __restrict__ pb, float* __restrict__ h) {
  __shared__ float xs[12];
  int m = blockIdx.y;
  int d = blockIdx.x * 256 + threadIdx.x;
  if (threadIdx.x < 12) xs[threadIdx.x] = x[m * 12 + threadIdx.x];
  __syncthreads();
  float acc = pb[d];
  #pragma unroll
  for (int j = 0; j < 12; j++) acc = fmaf(xs[j], pw[d * 12 + j], acc);
  h[(size_t)m * D_ + d] = acc;
}

// hn_bf16[m,:] = rmsnorm(h[m,:]) * w
__global__ __launch_bounds__(256) void k_rmsnorm_bf(const float* __restrict__ h, const float* __restrict__ w,
                                                    ushort* __restrict__ hn) {
  __shared__ float sm[4];
  int m = blockIdx.x, tid = threadIdx.x;
  const float* row = h + (size_t)m * D_;
  float v0 = row[tid], v1 = row[tid + 256], v2 = row[tid + 512];
  float s = block_sum(v0 * v0 + v1 * v1 + v2 * v2, sm);
  float sc = rsqrtf(s * (1.0f / D_) + EPS_);
  ushort* o = hn + (size_t)m * D_;
  o[tid]       = f2b(v0 * sc * w[tid]);
  o[tid + 256] = f2b(v1 * sc * w[tid + 256]);
  o[tid + 512] = f2b(v2 * sc * w[tid + 512]);
}

// C[M,Nd] = A_bf16[M,Kd] @ Bw_bf16[Nd,Kd]^T. MFMA 16x16x32 bf16.
// MODE 0: fp32 C=v  MODE 1: fp32 C=v+res[off]  MODE 2: fp32 C=softplus(v+res[col])
// MODE 3: bf16 C=v
template <int BM, int BN, int MODE>
__global__ __launch_bounds__(256) void k_gemm_bf(const ushort* __restrict__ A, const ushort* __restrict__ Bw,
                                                 void* __restrict__ Cv, const float* __restrict__ res,
                                                 int Kd, int Nd) {
  constexpr int AM = BM / 32, BNF = BN / 32;
  __shared__ ushort sA[BM * 32];
  __shared__ ushort sB[BN * 32];
  const int tid = threadIdx.x;
  const int wave = tid >> 6, lane = tid & 63;
  const int q = lane >> 4, r = lane & 15;
  const int wm = wave >> 1, wn = wave & 1;
  const int m0 = blockIdx.y * BM, n0 = blockIdx.x * BN;
  f32x4 acc[AM][BNF] = {};

  for (int k0 = 0; k0 < Kd; k0 += 32) {
    #pragma unroll
    for (int j = 0; j < BM / 64; j++) {
      int i = j * 256 + tid;
      const ushort* gp = A + (size_t)(m0 + (i >> 2)) * Kd + k0 + ((i & 3) << 3);
      __builtin_amdgcn_global_load_lds((gas_t)gp, (las_t)(sA + ((j * 256 + wave * 64) << 3)), 16, 0, 0);
    }
    #pragma unroll
    for (int j = 0; j < BN / 64; j++) {
      int i = j * 256 + tid;
      const ushort* gp = Bw + (size_t)(n0 + (i >> 2)) * Kd + k0 + ((i & 3) << 3);
      __builtin_amdgcn_global_load_lds((gas_t)gp, (las_t)(sB + ((j * 256 + wave * 64) << 3)), 16, 0, 0);
    }
    __syncthreads();
    bf16x8 af[AM], bfv[BNF];
    #pragma unroll
    for (int mi = 0; mi < AM; mi++)
      af[mi] = *(const bf16x8*)&sA[(wm * (BM / 2) + mi * 16 + r) * 32 + q * 8];
    #pragma unroll
    for (int nj = 0; nj < BNF; nj++)
      bfv[nj] = *(const bf16x8*)&sB[(wn * (BN / 2) + nj * 16 + r) * 32 + q * 8];
    #pragma unroll
    for (int mi = 0; mi < AM; mi++)
      #pragma unroll
      for (int nj = 0; nj < BNF; nj++)
        acc[mi][nj] = __builtin_amdgcn_mfma_f32_16x16x32_bf16(af[mi], bfv[nj], acc[mi][nj], 0, 0, 0);
    __syncthreads();
  }
  // C/D layout: col = lane&15, row = (lane>>4)*4 + reg
  #pragma unroll
  for (int mi = 0; mi < AM; mi++) {
    #pragma unroll
    for (int nj = 0; nj < BNF; nj++) {
      int col = n0 + wn * (BN / 2) + nj * 16 + r;
      #pragma unroll
      for (int rg = 0; rg < 4; rg++) {
        int row = m0 + wm * (BM / 2) + mi * 16 + q * 4 + rg;
        size_t off = (size_t)row * Nd + col;
        float v = acc[mi][nj][rg];
        if (MODE == 3) {
          ((ushort*)Cv)[off] = f2b(v);
        } else {
          if (MODE == 1) v += res[off];
          if (MODE == 2) v = softplusf(v + res[col]);
          ((float*)Cv)[off] = v;
        }
      }
    }
  }
}

// xproj GEMM, split-K: part[ks][M][80] = u_bf[M, ks-slice] @ xwb[80, ks-slice]^T
__global__ __launch_bounds__(256) void k_gemm_x(const ushort* __restrict__ A, const ushort* __restrict__ Bw,
                                                float* __restrict__ part) {
  __shared__ ushort sA[64 * 32];
  __shared__ ushort sB[80 * 32];
  const int tid = threadIdx.x;
  const int wave = tid >> 6, lane = tid & 63;
  const int q = lane >> 4, r = lane & 15;
  const int m0 = blockIdx.x * 64;
  const int kbeg = blockIdx.y * (E_ / KS_), kend = kbeg + E_ / KS_;
  f32x4 acc[5] = {};

  for (int k0 = kbeg; k0 < kend; k0 += 32) {
    {
      const ushort* gp = A + (size_t)(m0 + wave * 16 + (lane >> 2)) * E_ + k0 + ((lane & 3) << 3);
      __builtin_amdgcn_global_load_lds((gas_t)gp, (las_t)(sA + (wave << 9)), 16, 0, 0);
    }
    #pragma unroll
    for (int j = wave; j < 5; j += 4) {
      const ushort* gp = Bw + (size_t)(j * 16 + (lane >> 2)) * E_ + k0 + ((lane & 3) << 3);
      __builtin_amdgcn_global_load_lds((gas_t)gp, (las_t)(sB + (j << 9)), 16, 0, 0);
    }
    __syncthreads();
    bf16x8 af = *(const bf16x8*)&sA[(wave * 16 + r) * 32 + q * 8];
    #pragma unroll
    for (int nj = 0; nj < 5; nj++) {
      bf16x8 bfv = *(const bf16x8*)&sB[(nj * 16 + r) * 32 + q * 8];
      acc[nj] = __builtin_amdgcn_mfma_f32_16x16x32_bf16(af, bfv, acc[nj], 0, 0, 0);
    }
    __syncthreads();
  }
  float* pp = part + (size_t)blockIdx.y * M_ * XD_;
  #pragma unroll
  for (int nj = 0; nj < 5; nj++) {
    int col = nj * 16 + r;
    #pragma unroll
    for (int rg = 0; rg < 4; rg++) {
      int row = m0 + wave * 16 + q * 4 + rg;
      pp[(size_t)row * XD_ + col] = acc[nj][rg];
    }
  }
}

// combine split-K partials -> xdbc fp32 [M][80] + bf16 dt-input copy [M][64]
__global__ __launch_bounds__(256) void k_xfin(const float* __restrict__ part, float* __restrict__ xdbc,
                                              ushort* __restrict__ xb) {
  int i = blockIdx.x * 256 + threadIdx.x;   // over M*80
  int m = i / XD_, col = i - m * XD_;
  float s = 0.0f;
  #pragma unroll
  for (int ks = 0; ks < KS_; ks++) s += part[(size_t)ks * M_ * XD_ + i];
  xdbc[i] = s;
  if (col < R_) xb[(size_t)m * 64 + col] = f2b(s);
  else if (col < 64) xb[(size_t)m * 64 + col] = 0;
}

// conv + silu for u; silu for gate. bf16 in (proj_bf), bf16 out. 4 e / thread.
__global__ __launch_bounds__(384) void k_conv2(const ushort* __restrict__ proj, const float* __restrict__ cw,
                                               const float* __restrict__ cb, ushort* __restrict__ ub16,
                                               ushort* __restrict__ gb16) {
  int m = blockIdx.x;
  int b = m >> 10, t = m & (L_ - 1);
  int e4 = threadIdx.x * 4;
  float wv[4][4];
  #pragma unroll
  for (int j = 0; j < 4; j++) {
    float4 w = *(const float4*)(cw + (e4 + j) * 4);
    wv[j][0] = w.x; wv[j][1] = w.y; wv[j][2] = w.z; wv[j][3] = w.w;
  }
  float4 bb = *(const float4*)(cb + e4);
  float acc[4] = {bb.x, bb.y, bb.z, bb.w};
  #pragma unroll
  for (int k = 0; k < 4; k++) {
    int tt = t + k - 3;
    if (tt >= 0) {
      uint2 p = *(const uint2*)(proj + (size_t)(b * L_ + tt) * E2_ + e4);
      acc[0] = fmaf(wv[0][k], b2f_lo(p.x), acc[0]);
      acc[1] = fmaf(wv[1][k], b2f_hi(p.x), acc[1]);
      acc[2] = fmaf(wv[2][k], b2f_lo(p.y), acc[2]);
      acc[3] = fmaf(wv[3][k], b2f_hi(p.y), acc[3]);
    }
  }
  uint2 uo;
  {
    float u0 = acc[0] * sigm(acc[0]), u1 = acc[1] * sigm(acc[1]);
    float u2 = acc[2] * sigm(acc[2]), u3 = acc[3] * sigm(acc[3]);
    uo.x = (unsigned)f2b(u0) | ((unsigned)f2b(u1) << 16);
    uo.y = (unsigned)f2b(u2) | ((unsigned)f2b(u3) << 16);
  }
  *(uint2*)(ub16 + (size_t)m * E_ + e4) = uo;
  // gate -> silu -> bf16
  uint2 g = *(const uint2*)(proj + (size_t)m * E2_ + E_ + e4);
  float g0 = b2f_lo(g.x), g1 = b2f_hi(g.x), g2 = b2f_lo(g.y), g3 = b2f_hi(g.y);
  g0 *= sigm(g0); g1 *= sigm(g1); g2 *= sigm(g2); g3 *= sigm(g3);
  uint2 go;
  go.x = (unsigned)f2b(g0) | ((unsigned)f2b(g1) << 16);
  go.y = (unsigned)f2b(g2) | ((unsigned)f2b(g3) << 16);
  *(uint2*)(gb16 + (size_t)m * E_ + e4) = go;
}

// ---- Parallel (chunked) selective scan, single-shot chunk staging -----------
__global__ __launch_bounds__(256, 6) void k_scanA(const ushort* __restrict__ u, const float* __restrict__ dtb,
                                                  const float* __restrict__ xdbc, const float* __restrict__ A_log,
                                                  float* __restrict__ Pst, float* __restrict__ Sst) {
  __shared__ float2 s_dtu[CL_][16];
  __shared__ float  s_b [CL_][16];
  const int tid = threadIdx.x;
  const int e0 = blockIdx.x << 4;
  const int b  = blockIdx.y;
  const int c  = blockIdx.z;
  const int n  = tid & 15, el = tid >> 4;
  const int e  = e0 + el;
  const float A = -__expf(A_log[e * N_ + n]);
  const int t0 = c * CL_;

  float r_dt[4], r_b[4];
  ushort r_u[4];
  #pragma unroll
  for (int j = 0; j < 4; j++) {
    size_t m = (size_t)(b * L_ + t0 + j * 16 + el);
    r_dt[j] = dtb[m * E_ + e0 + n];
    r_u[j]  = u[m * E_ + e0 + n];
    int idx = j * 256 + tid;
    r_b[j] = xdbc[(size_t)(b * L_ + t0 + (idx >> 4)) * XD_ + R_ + (idx & 15)];
  }
  #pragma unroll
  for (int j = 0; j < 4; j++) {
    int t = j * 16 + el;
    s_dtu[t][n] = make_float2(r_dt[j], r_dt[j] * b2f(r_u[j]));
    int idx = j * 256 + tid;
    s_b[idx >> 4][idx & 15] = r_b[j];
  }
  __syncthreads();

  float hs = 0.0f, pp = 1.0f;
  #pragma unroll 8
  for (int t = 0; t < CL_; t++) {
    float2 dtu = s_dtu[t][el];
    float dA = __expf(dtu.x * A);
    hs = fmaf(hs, dA, dtu.y * s_b[t][n]);
    pp *= dA;
  }
  size_t o = (((size_t)(b * NCH_ + c) * E_) + e) * N_ + n;
  Pst[o] = pp;
  Sst[o] = hs;
}

__global__ __launch_bounds__(256, 6) void k_scanC(const ushort* __restrict__ u, const float* __restrict__ dtb,
                                                  const float* __restrict__ xdbc, const ushort* __restrict__ gb,
                                                  const float* __restrict__ A_log, const float* __restrict__ Dp,
                                                  const float* __restrict__ Pst, const float* __restrict__ Sst,
                                                  ushort* __restrict__ y) {
  __shared__ float2 s_dtu[CL_][16];
  __shared__ float2 s_bc [CL_][16];
  __shared__ float2 s_og [CL_][16];
  __shared__ ushort s_y [CL_][16];
  const int tid = threadIdx.x;
  const int e0 = blockIdx.x << 4;
  const int b  = blockIdx.y;
  const int c  = blockIdx.z;
  const int n  = tid & 15, el = tid >> 4;
  const int e  = e0 + el;
  const float A = -__expf(A_log[e * N_ + n]);
  const float Dv = Dp[e0 + n];
  const int t0 = c * CL_;

  float r_dt[4], r_bc[8];
  ushort r_u[4], r_g[4];
  #pragma unroll
  for (int j = 0; j < 4; j++) {
    size_t m = (size_t)(b * L_ + t0 + j * 16 + el);
    r_dt[j] = dtb[m * E_ + e0 + n];
    r_u[j]  = u[m * E_ + e0 + n];
    r_g[j]  = gb[m * E_ + e0 + n];
  }
  #pragma unroll
  for (int j = 0; j < 8; j++) {
    int idx = j * 256 + tid;
    r_bc[j] = xdbc[(size_t)(b * L_ + t0 + (idx >> 5)) * XD_ + R_ + (idx & 31)];
  }

  // branchless parallel lookback over predecessor chunk summaries
  float hs = 0.0f;
  if (c > 0) {
    float pv[NCH_ - 1], sv[NCH_ - 1];
    #pragma unroll
    for (int cc = 0; cc < NCH_ - 1; cc++) {
      int ci = cc < c ? cc : c - 1;
      size_t o = (((size_t)(b * NCH_ + ci) * E_) + e) * N_ + n;
      pv[cc] = Pst[o];
      sv[cc] = Sst[o];
    }
    #pragma unroll
    for (int cc = 0; cc < NCH_ - 1; cc++) {
      bool v = cc < c;
      hs = fmaf(v ? pv[cc] : 1.0f, hs, v ? sv[cc] : 0.0f);
    }
  }

  #pragma unroll
  for (int j = 0; j < 4; j++) {
    int t = j * 16 + el;
    float uf = b2f(r_u[j]);
    s_dtu[t][n] = make_float2(r_dt[j], r_dt[j] * uf);
    s_og[t][n] = make_float2(uf * Dv, b2f(r_g[j]));
  }
  #pragma unroll
  for (int j = 0; j < 8; j++) {
    int idx = j * 256 + tid;
    int t = idx >> 5, col = idx & 31;
    ((float*)&s_bc[t][0])[((col & 15) << 1) + (col >> 4)] = r_bc[j];
  }
  __syncthreads();

  #pragma unroll 8
  for (int t = 0; t < CL_; t++) {
    float2 dtu = s_dtu[t][el];
    float2 bc  = s_bc[t][n];
    float dA = __expf(dtu.x * A);
    hs = fmaf(hs, dA, dtu.y * bc.x);
    float p = row_sum16(hs * bc.y);
    if (n == 0) {
      float2 og = s_og[t][el];
      s_y[t][el] = f2b((p + og.x) * og.y);
    }
  }
  __syncthreads();

  {
    int row = tid >> 2, seg = tid & 3;
    uint2 v = *(const uint2*)&s_y[row][seg * 4];
    *(uint2*)(y + (size_t)(b * L_ + t0 + row) * E_ + e0 + seg * 4) = v;
  }
}

// rs[m] = rsqrt(mean(h[m,:]^2)+eps)
__global__ __launch_bounds__(256) void k_rowscale(const float* __restrict__ h, float* __restrict__ rs) {
  __shared__ float sm[4];
  int m = blockIdx.x, tid = threadIdx.x;
  const float* row = h + (size_t)m * D_;
  float v0 = row[tid], v1 = row[tid + 256], v2 = row[tid + 512];
  float s = block_sum(v0 * v0 + v1 * v1 + v2 * v2, sm);
  if (tid == 0) rs[m] = rsqrtf(s * (1.0f / D_) + EPS_);
}

// partial pool: pooledP[pc][b][d] = sum over the pc-th t-chunk of h*rs (no atomics/memset)
__global__ __launch_bounds__(256) void k_pool(const float* __restrict__ h, const float* __restrict__ rs,
                                              float* __restrict__ pooledP) {
  int d = blockIdx.x * 256 + threadIdx.x;
  int pc = blockIdx.y;
  int b = blockIdx.z;
  int t0 = pc * (L_ / PC_);
  float acc = 0.0f;
  for (int t = t0; t < t0 + L_ / PC_; t++) {
    int m = b * L_ + t;
    acc = fmaf(h[(size_t)m * D_ + d], rs[m], acc);
  }
  pooledP[((size_t)pc * B_ + b) * D_ + d] = acc;
}

// out[b,c]: cooperative LDS reduce of pooledP (coalesced), then wave-dot from LDS.
__global__ __launch_bounds__(256) void k_logits(const float* __restrict__ pooledP, const float* __restrict__ fw,
                                                const float* __restrict__ cw, const float* __restrict__ cb,
                                                float* __restrict__ out) {
  __shared__ float sp[B_ * D_];   // 6 KB
  int tid = threadIdx.x;
  for (int d = tid; d < B_ * D_; d += 256) {
    int b = d / D_, dd = d - b * D_;
    float pd = 0.0f;
    #pragma unroll
    for (int pc = 0; pc < PC_; pc++) pd += pooledP[((size_t)pc * B_ + b) * D_ + dd];
    sp[d] = pd * fw[dd] * (1.0f / L_);
  }
  __syncthreads();
  int wv = tid >> 6, ln = tid & 63;
  for (int p = wv; p < B_ * NC_; p += 4) {
    int b = p / NC_, c = p % NC_;
    float s = 0.0f;
    for (int d = ln; d < D_; d += 64) s = fmaf(sp[b * D_ + d], cw[c * D_ + d], s);
    #pragma unroll
    for (int o = 32; o > 0; o >>= 1) s += __shfl_xor(s, o);
    if (ln == 0) out[p] = s + cb[c];
  }
}

extern "C" void kernel_launch(void* const* d_in, const int* in_sizes, int n_in,
                              void* d_out, int out_size, void* d_ws, size_t ws_size,
                              hipStream_t stream) {
  const float* x       = (const float*)d_in[0];
  const float* proj_w  = (const float*)d_in[1];
  const float* proj_b  = (const float*)d_in[2];
  const float* norm_w  = (const float*)d_in[3];
  const float* in_w    = (const float*)d_in[4];
  const float* conv_w  = (const float*)d_in[5];
  const float* conv_b  = (const float*)d_in[6];
  const float* xproj_w = (const float*)d_in[7];
  const float* dt_w    = (const float*)d_in[8];
  const float* dt_b    = (const float*)d_in[9];
  const float* A_log   = (const float*)d_in[10];
  const float* D_param = (const float*)d_in[11];
  const float* out_w   = (const float*)d_in[12];
  const float* fnorm_w = (const float*)d_in[13];
  const float* cls_w   = (const float*)d_in[14];
  const float* cls_b   = (const float*)d_in[15];
  float* out = (float*)d_out;

  // workspace layout
  float* h      = (float*)d_ws;                         // M*D
  float* xdbc   = h + (size_t)M_ * D_;                  // M*80
  float* dtbuf  = xdbc + (size_t)M_ * XD_;              // M*E fp32 dt
  float* rsb    = dtbuf + (size_t)M_ * E_;              // M
  float* pooledP = rsb + M_;                            // PC*B*D
  float* Pst    = pooledP + (size_t)PC_ * B_ * D_;      // B*NCH*E*N
  float* Sst    = Pst + (size_t)B_ * NCH_ * E_ * N_;    // B*NCH*E*N
  float* xpart  = Sst + (size_t)B_ * NCH_ * E_ * N_;    // KS*M*80
  ushort* proj_bf = (ushort*)(xpart + (size_t)KS_ * M_ * XD_);  // M*2E bf16
  ushort* hn_bf   = proj_bf + (size_t)M_ * E2_;         // M*D
  ushort* y_bf    = hn_bf + (size_t)M_ * D_;            // M*E
  ushort* ub_bf   = y_bf + (size_t)M_ * E_;             // M*E
  ushort* g_bf    = ub_bf + (size_t)M_ * E_;            // M*E
  ushort* xdbc_bf = g_bf + (size_t)M_ * E_;             // M*64
  ushort* xwb     = xdbc_bf + (size_t)M_ * 64;          // NL*80*E
  ushort* dtwb    = xwb + (size_t)NL_ * XD_ * E_;       // NL*E*64
  ushort* in_wb   = dtwb + (size_t)NL_ * E_ * 64;       // NL*E2*D
  ushort* out_wb  = in_wb + (size_t)NL_ * E2_ * D_;     // NL*D*E

  constexpr int WTOT = WS1_ + WS2_ + WS3_ + WS4_;
  k_wprep<<<(WTOT / 4 + 255) / 256, 256, 0, stream>>>(in_w, out_w, xproj_w, dt_w,
                                                      in_wb, out_wb, xwb, dtwb);

  k_proj<<<dim3(D_ / 256, M_), 256, 0, stream>>>(x, proj_w, proj_b, h);

  for (int i = 0; i < NL_; i++) {
    k_rmsnorm_bf<<<M_, 256, 0, stream>>>(h, norm_w + i * D_, hn_bf);
    k_gemm_bf<64, 128, 3><<<dim3(E2_ / 128, M_ / 64), 256, 0, stream>>>(
        hn_bf, in_wb + (size_t)i * E2_ * D_, proj_bf, nullptr, D_, E2_);
    k_conv2<<<M_, 384, 0, stream>>>(proj_bf, conv_w + i * E_ * 4, conv_b + i * E_, ub_bf, g_bf);
    k_gemm_x<<<dim3(M_ / 64, KS_), 256, 0, stream>>>(ub_bf, xwb + (size_t)i * XD_ * E_, xpart);
    k_xfin<<<M_ * XD_ / 256, 256, 0, stream>>>(xpart, xdbc, xdbc_bf);
    k_gemm_bf<64, 64, 2><<<dim3(E_ / 64, M_ / 64), 256, 0, stream>>>(
        xdbc_bf, dtwb + (size_t)i * E_ * 64, dtbuf, dt_b + i * E_, 64, E_);
    k_scanA<<<dim3(E_ / 16, B_, NCH_), 256, 0, stream>>>(ub_bf, dtbuf, xdbc,
                                                         A_log + (size_t)i * E_ * N_, Pst, Sst);
    k_scanC<<<dim3(E_ / 16, B_, NCH_), 256, 0, stream>>>(ub_bf, dtbuf, xdbc, g_bf,
                                                         A_log + (size_t)i * E_ * N_, D_param + i * E_,
                                                         Pst, Sst, y_bf);
    k_gemm_bf<64, 64, 1><<<dim3(D_ / 64, M_ / 64), 256, 0, stream>>>(
        y_bf, out_wb + (size_t)i * D_ * E_, h, h, E_, D_);
  }

  k_rowscale<<<M_, 256, 0, stream>>>(h, rsb);
  k_pool<<<dim3(D_ / 256, PC_, B_), 256, 0, stream>>>(h, rsb, pooledP);
  k_logits<<<1, 256, 0, stream>>>(pooledP, fnorm_w, cls_w, cls_b, out);
}

// Round 12
// 674.279 us; speedup vs baseline: 1.2559x; 1.0145x over previous
//
#include <hip/hip_runtime.h>

// Problem constants (match reference)
constexpr int B_  = 2;
constexpr int L_  = 1024;
constexpr int D_  = 768;
constexpr int E_  = 1536;
constexpr int N_  = 16;
constexpr int R_  = 48;
constexpr int NL_ = 4;
constexpr int NC_ = 5;
constexpr int M_  = B_ * L_;        // 2048 token rows
constexpr int E2_ = 2 * E_;         // 3072
constexpr int XD_ = R_ + 2 * N_;    // 80
constexpr float EPS_ = 1e-5f;

constexpr int NCH_ = 16;            // time-chunks for parallel scan
constexpr int CL_  = L_ / NCH_;     // 64 timesteps per chunk
constexpr int KS_  = 8;             // split-K factor for xproj GEMM
constexpr int PC_  = 8;             // t-chunks for final pool

typedef __attribute__((ext_vector_type(8))) short bf16x8;
typedef __attribute__((ext_vector_type(4))) float f32x4;
typedef const __attribute__((address_space(1))) void* gas_t;
typedef __attribute__((address_space(3))) void* las_t;

__device__ __forceinline__ float sigm(float x) { return 1.0f / (1.0f + __expf(-x)); }
__device__ __forceinline__ float softplusf(float x) { return x > 20.0f ? x : log1pf(__expf(x)); }
__device__ __forceinline__ ushort f2b(float f) {  // fp32 -> bf16 RNE
  union { float f; unsigned u; } v; v.f = f;
  unsigned r = (v.u + 0x7fffu + ((v.u >> 16) & 1u)) >> 16;
  return (ushort)r;
}
__device__ __forceinline__ float b2f(ushort u) {
  union { unsigned u; float f; } v; v.u = ((unsigned)u) << 16;
  return v.f;
}
__device__ __forceinline__ float b2f_lo(unsigned p) {
  union { unsigned u; float f; } v; v.u = p << 16;
  return v.f;
}
__device__ __forceinline__ float b2f_hi(unsigned p) {
  union { unsigned u; float f; } v; v.u = p & 0xffff0000u;
  return v.f;
}

// DPP row_ror add: sum over 16-lane rows, full-rate VALU
template <int CTRL>
__device__ __forceinline__ float dpp_add(float x) {
  int yi = __builtin_amdgcn_update_dpp(0, __builtin_bit_cast(int, x), CTRL, 0xf, 0xf, false);
  return x + __builtin_bit_cast(float, yi);
}
__device__ __forceinline__ float row_sum16(float x) {
  x = dpp_add<0x121>(x);
  x = dpp_add<0x122>(x);
  x = dpp_add<0x124>(x);
  x = dpp_add<0x128>(x);
  return x;
}

__device__ __forceinline__ float block_sum(float v, float* sm) {
  #pragma unroll
  for (int o = 32; o > 0; o >>= 1) v += __shfl_xor(v, o);
  if ((threadIdx.x & 63) == 0) sm[threadIdx.x >> 6] = v;
  __syncthreads();
  return sm[0] + sm[1] + sm[2] + sm[3];
}

// One-shot prep: weight f2b conversions (in_w, out_w, xproj_w; dt_w padded 48->64)
// PLUS the input projection h = x @ proj_w^T + proj_b (merged to save one dispatch).
constexpr int WS1_ = NL_ * E2_ * D_;
constexpr int WS2_ = NL_ * D_ * E_;
constexpr int WS3_ = NL_ * XD_ * E_;
constexpr int WS4_ = NL_ * E_ * 64;
constexpr int WTOT_ = WS1_ + WS2_ + WS3_ + WS4_;
constexpr int WB_ = WTOT_ / 4 / 256;            // weight-conv blocks (exact: 14688)
__global__ __launch_bounds__(256) void k_wprep(const float* __restrict__ in_w, const float* __restrict__ out_w,
                                               const float* __restrict__ xw, const float* __restrict__ dw,
                                               ushort* __restrict__ in_wb, ushort* __restrict__ out_wb,
                                               ushort* __restrict__ xwb, ushort* __restrict__ dtwb,
                                               const float* __restrict__ x, const float* __restrict__ pw,
                                               const float* __restrict__ pb, float* __restrict__ h) {
  if (blockIdx.x >= WB_) {
    // input projection: 3 blocks per token row
    __shared__ float xs[12];
    int bx = blockIdx.x - WB_;
    int m = bx / 3;
    int d = (bx % 3) * 256 + threadIdx.x;
    if (threadIdx.x < 12) xs[threadIdx.x] = x[m * 12 + threadIdx.x];
    __syncthreads();
    float acc = pb[d];
    #pragma unroll
    for (int j = 0; j < 12; j++) acc = fmaf(xs[j], pw[d * 12 + j], acc);
    h[(size_t)m * D_ + d] = acc;
    return;
  }
  int i = (blockIdx.x * 256 + threadIdx.x) * 4;
  if (i < WS1_) {
    float4 v = *(const float4*)(in_w + i);
    *(ushort4*)(in_wb + i) = make_ushort4(f2b(v.x), f2b(v.y), f2b(v.z), f2b(v.w));
  } else if (i < WS1_ + WS2_) {
    int j = i - WS1_;
    float4 v = *(const float4*)(out_w + j);
    *(ushort4*)(out_wb + j) = make_ushort4(f2b(v.x), f2b(v.y), f2b(v.z), f2b(v.w));
  } else if (i < WS1_ + WS2_ + WS3_) {
    int j = i - WS1_ - WS2_;
    float4 v = *(const float4*)(xw + j);
    *(ushort4*)(xwb + j) = make_ushort4(f2b(v.x), f2b(v.y), f2b(v.z), f2b(v.w));
  } else {
    int j = i - WS1_ - WS2_ - WS3_;
    int k = j & 63, e = j >> 6;
    ushort4 o;
    o.x = (k + 0 < R_) ? f2b(dw[e * R_ + k + 0]) : (ushort)0;
    o.y = (k + 1 < R_) ? f2b(dw[e * R_ + k + 1]) : (ushort)0;
    o.z = (k + 2 < R_) ? f2b(dw[e * R_ + k + 2]) : (ushort)0;
    o.w = (k + 3 < R_) ? f2b(dw[e * R_ + k + 3]) : (ushort)0;
    *(ushort4*)(dtwb + j) = o;
  }
}

// hn_bf16[m,:] = rmsnorm(h[m,:]) * w
__global__ __launch_bounds__(256) void k_rmsnorm_bf(const float* __restrict__ h, const float* __restrict__ w,
                                                    ushort* __restrict__ hn) {
  __shared__ float sm[4];
  int m = blockIdx.x, tid = threadIdx.x;
  const float* row = h + (size_t)m * D_;
  float v0 = row[tid], v1 = row[tid + 256], v2 = row[tid + 512];
  float s = block_sum(v0 * v0 + v1 * v1 + v2 * v2, sm);
  float sc = rsqrtf(s * (1.0f / D_) + EPS_);
  ushort* o = hn + (size_t)m * D_;
  o[tid]       = f2b(v0 * sc * w[tid]);
  o[tid + 256] = f2b(v1 * sc * w[tid + 256]);
  o[tid + 512] = f2b(v2 * sc * w[tid + 512]);
}

// C[M,Nd] = A_bf16[M,Kd] @ Bw_bf16[Nd,Kd]^T. MFMA 16x16x32 bf16.
// Requires BN % 128 == 0 OR BN=192 (wave-n covers BN/2 in 16-col tiles).
// MODE 0: fp32 C=v  MODE 1: fp32 C=v+res[off]  MODE 2: fp32 C=softplus(v+res[col])
// MODE 3: bf16 C=v
template <int BM, int BN, int MODE>
__global__ __launch_bounds__(256) void k_gemm_bf(const ushort* __restrict__ A, const ushort* __restrict__ Bw,
                                                 void* __restrict__ Cv, const float* __restrict__ res,
                                                 int Kd, int Nd) {
  constexpr int AM = BM / 32, BNF = BN / 32;
  __shared__ ushort sA[BM * 32];
  __shared__ ushort sB[BN * 32];
  const int tid = threadIdx.x;
  const int wave = tid >> 6, lane = tid & 63;
  const int q = lane >> 4, r = lane & 15;
  const int wm = wave >> 1, wn = wave & 1;
  const int m0 = blockIdx.y * BM, n0 = blockIdx.x * BN;
  f32x4 acc[AM][BNF] = {};

  for (int k0 = 0; k0 < Kd; k0 += 32) {
    #pragma unroll
    for (int j = 0; j < BM / 64; j++) {
      int i = j * 256 + tid;
      const ushort* gp = A + (size_t)(m0 + (i >> 2)) * Kd + k0 + ((i & 3) << 3);
      __builtin_amdgcn_global_load_lds((gas_t)gp, (las_t)(sA + ((j * 256 + wave * 64) << 3)), 16, 0, 0);
    }
    #pragma unroll
    for (int j = 0; j < BN / 64; j++) {
      int i = j * 256 + tid;
      const ushort* gp = Bw + (size_t)(n0 + (i >> 2)) * Kd + k0 + ((i & 3) << 3);
      __builtin_amdgcn_global_load_lds((gas_t)gp, (las_t)(sB + ((j * 256 + wave * 64) << 3)), 16, 0, 0);
    }
    __syncthreads();
    bf16x8 af[AM], bfv[BNF];
    #pragma unroll
    for (int mi = 0; mi < AM; mi++)
      af[mi] = *(const bf16x8*)&sA[(wm * (BM / 2) + mi * 16 + r) * 32 + q * 8];
    #pragma unroll
    for (int nj = 0; nj < BNF; nj++)
      bfv[nj] = *(const bf16x8*)&sB[(wn * (BN / 2) + nj * 16 + r) * 32 + q * 8];
    #pragma unroll
    for (int mi = 0; mi < AM; mi++)
      #pragma unroll
      for (int nj = 0; nj < BNF; nj++)
        acc[mi][nj] = __builtin_amdgcn_mfma_f32_16x16x32_bf16(af[mi], bfv[nj], acc[mi][nj], 0, 0, 0);
    __syncthreads();
  }
  // C/D layout: col = lane&15, row = (lane>>4)*4 + reg
  #pragma unroll
  for (int mi = 0; mi < AM; mi++) {
    #pragma unroll
    for (int nj = 0; nj < BNF; nj++) {
      int col = n0 + wn * (BN / 2) + nj * 16 + r;
      #pragma unroll
      for (int rg = 0; rg < 4; rg++) {
        int row = m0 + wm * (BM / 2) + mi * 16 + q * 4 + rg;
        size_t off = (size_t)row * Nd + col;
        float v = acc[mi][nj][rg];
        if (MODE == 3) {
          ((ushort*)Cv)[off] = f2b(v);
        } else {
          if (MODE == 1) v += res[off];
          if (MODE == 2) v = softplusf(v + res[col]);
          ((float*)Cv)[off] = v;
        }
      }
    }
  }
}

// xproj GEMM, split-K: part[ks][M][80] = u_bf[M, ks-slice] @ xwb[80, ks-slice]^T
__global__ __launch_bounds__(256) void k_gemm_x(const ushort* __restrict__ A, const ushort* __restrict__ Bw,
                                                float* __restrict__ part) {
  __shared__ ushort sA[64 * 32];
  __shared__ ushort sB[80 * 32];
  const int tid = threadIdx.x;
  const int wave = tid >> 6, lane = tid & 63;
  const int q = lane >> 4, r = lane & 15;
  const int m0 = blockIdx.x * 64;
  const int kbeg = blockIdx.y * (E_ / KS_), kend = kbeg + E_ / KS_;
  f32x4 acc[5] = {};

  for (int k0 = kbeg; k0 < kend; k0 += 32) {
    {
      const ushort* gp = A + (size_t)(m0 + wave * 16 + (lane >> 2)) * E_ + k0 + ((lane & 3) << 3);
      __builtin_amdgcn_global_load_lds((gas_t)gp, (las_t)(sA + (wave << 9)), 16, 0, 0);
    }
    #pragma unroll
    for (int j = wave; j < 5; j += 4) {
      const ushort* gp = Bw + (size_t)(j * 16 + (lane >> 2)) * E_ + k0 + ((lane & 3) << 3);
      __builtin_amdgcn_global_load_lds((gas_t)gp, (las_t)(sB + (j << 9)), 16, 0, 0);
    }
    __syncthreads();
    bf16x8 af = *(const bf16x8*)&sA[(wave * 16 + r) * 32 + q * 8];
    #pragma unroll
    for (int nj = 0; nj < 5; nj++) {
      bf16x8 bfv = *(const bf16x8*)&sB[(nj * 16 + r) * 32 + q * 8];
      acc[nj] = __builtin_amdgcn_mfma_f32_16x16x32_bf16(af, bfv, acc[nj], 0, 0, 0);
    }
    __syncthreads();
  }
  float* pp = part + (size_t)blockIdx.y * M_ * XD_;
  #pragma unroll
  for (int nj = 0; nj < 5; nj++) {
    int col = nj * 16 + r;
    #pragma unroll
    for (int rg = 0; rg < 4; rg++) {
      int row = m0 + wave * 16 + q * 4 + rg;
      pp[(size_t)row * XD_ + col] = acc[nj][rg];
    }
  }
}

// combine split-K partials -> xdbc fp32 [M][80] + bf16 dt-input copy [M][64]
__global__ __launch_bounds__(256) void k_xfin(const float* __restrict__ part, float* __restrict__ xdbc,
                                              ushort* __restrict__ xb) {
  int i = blockIdx.x * 256 + threadIdx.x;   // over M*80
  int m = i / XD_, col = i - m * XD_;
  float s = 0.0f;
  #pragma unroll
  for (int ks = 0; ks < KS_; ks++) s += part[(size_t)ks * M_ * XD_ + i];
  xdbc[i] = s;
  if (col < R_) xb[(size_t)m * 64 + col] = f2b(s);
  else if (col < 64) xb[(size_t)m * 64 + col] = 0;
}

// conv + silu for u; silu for gate. bf16 in (proj_bf), bf16 out. 4 e / thread.
__global__ __launch_bounds__(384) void k_conv2(const ushort* __restrict__ proj, const float* __restrict__ cw,
                                               const float* __restrict__ cb, ushort* __restrict__ ub16,
                                               ushort* __restrict__ gb16) {
  int m = blockIdx.x;
  int b = m >> 10, t = m & (L_ - 1);
  int e4 = threadIdx.x * 4;
  float wv[4][4];
  #pragma unroll
  for (int j = 0; j < 4; j++) {
    float4 w = *(const float4*)(cw + (e4 + j) * 4);
    wv[j][0] = w.x; wv[j][1] = w.y; wv[j][2] = w.z; wv[j][3] = w.w;
  }
  float4 bb = *(const float4*)(cb + e4);
  float acc[4] = {bb.x, bb.y, bb.z, bb.w};
  #pragma unroll
  for (int k = 0; k < 4; k++) {
    int tt = t + k - 3;
    if (tt >= 0) {
      uint2 p = *(const uint2*)(proj + (size_t)(b * L_ + tt) * E2_ + e4);
      acc[0] = fmaf(wv[0][k], b2f_lo(p.x), acc[0]);
      acc[1] = fmaf(wv[1][k], b2f_hi(p.x), acc[1]);
      acc[2] = fmaf(wv[2][k], b2f_lo(p.y), acc[2]);
      acc[3] = fmaf(wv[3][k], b2f_hi(p.y), acc[3]);
    }
  }
  uint2 uo;
  {
    float u0 = acc[0] * sigm(acc[0]), u1 = acc[1] * sigm(acc[1]);
    float u2 = acc[2] * sigm(acc[2]), u3 = acc[3] * sigm(acc[3]);
    uo.x = (unsigned)f2b(u0) | ((unsigned)f2b(u1) << 16);
    uo.y = (unsigned)f2b(u2) | ((unsigned)f2b(u3) << 16);
  }
  *(uint2*)(ub16 + (size_t)m * E_ + e4) = uo;
  // gate -> silu -> bf16
  uint2 g = *(const uint2*)(proj + (size_t)m * E2_ + E_ + e4);
  float g0 = b2f_lo(g.x), g1 = b2f_hi(g.x), g2 = b2f_lo(g.y), g3 = b2f_hi(g.y);
  g0 *= sigm(g0); g1 *= sigm(g1); g2 *= sigm(g2); g3 *= sigm(g3);
  uint2 go;
  go.x = (unsigned)f2b(g0) | ((unsigned)f2b(g1) << 16);
  go.y = (unsigned)f2b(g2) | ((unsigned)f2b(g3) << 16);
  *(uint2*)(gb16 + (size_t)m * E_ + e4) = go;
}

// ---- Parallel (chunked) selective scan, single-shot chunk staging -----------
__global__ __launch_bounds__(256, 6) void k_scanA(const ushort* __restrict__ u, const float* __restrict__ dtb,
                                                  const float* __restrict__ xdbc, const float* __restrict__ A_log,
                                                  float* __restrict__ Pst, float* __restrict__ Sst) {
  __shared__ float2 s_dtu[CL_][16];
  __shared__ float  s_b [CL_][16];
  const int tid = threadIdx.x;
  const int e0 = blockIdx.x << 4;
  const int b  = blockIdx.y;
  const int c  = blockIdx.z;
  const int n  = tid & 15, el = tid >> 4;
  const int e  = e0 + el;
  const float A = -__expf(A_log[e * N_ + n]);
  const int t0 = c * CL_;

  float r_dt[4], r_b[4];
  ushort r_u[4];
  #pragma unroll
  for (int j = 0; j < 4; j++) {
    size_t m = (size_t)(b * L_ + t0 + j * 16 + el);
    r_dt[j] = dtb[m * E_ + e0 + n];
    r_u[j]  = u[m * E_ + e0 + n];
    int idx = j * 256 + tid;
    r_b[j] = xdbc[(size_t)(b * L_ + t0 + (idx >> 4)) * XD_ + R_ + (idx & 15)];
  }
  #pragma unroll
  for (int j = 0; j < 4; j++) {
    int t = j * 16 + el;
    s_dtu[t][n] = make_float2(r_dt[j], r_dt[j] * b2f(r_u[j]));
    int idx = j * 256 + tid;
    s_b[idx >> 4][idx & 15] = r_b[j];
  }
  __syncthreads();

  float hs = 0.0f, pp = 1.0f;
  #pragma unroll 8
  for (int t = 0; t < CL_; t++) {
    float2 dtu = s_dtu[t][el];
    float dA = __expf(dtu.x * A);
    hs = fmaf(hs, dA, dtu.y * s_b[t][n]);
    pp *= dA;
  }
  size_t o = (((size_t)(b * NCH_ + c) * E_) + e) * N_ + n;
  Pst[o] = pp;
  Sst[o] = hs;
}

__global__ __launch_bounds__(256, 6) void k_scanC(const ushort* __restrict__ u, const float* __restrict__ dtb,
                                                  const float* __restrict__ xdbc, const ushort* __restrict__ gb,
                                                  const float* __restrict__ A_log, const float* __restrict__ Dp,
                                                  const float* __restrict__ Pst, const float* __restrict__ Sst,
                                                  ushort* __restrict__ y) {
  __shared__ float2 s_dtu[CL_][16];
  __shared__ float2 s_bc [CL_][16];
  __shared__ float2 s_og [CL_][16];
  __shared__ ushort s_y [CL_][16];
  const int tid = threadIdx.x;
  const int e0 = blockIdx.x << 4;
  const int b  = blockIdx.y;
  const int c  = blockIdx.z;
  const int n  = tid & 15, el = tid >> 4;
  const int e  = e0 + el;
  const float A = -__expf(A_log[e * N_ + n]);
  const float Dv = Dp[e0 + n];
  const int t0 = c * CL_;

  float r_dt[4], r_bc[8];
  ushort r_u[4], r_g[4];
  #pragma unroll
  for (int j = 0; j < 4; j++) {
    size_t m = (size_t)(b * L_ + t0 + j * 16 + el);
    r_dt[j] = dtb[m * E_ + e0 + n];
    r_u[j]  = u[m * E_ + e0 + n];
    r_g[j]  = gb[m * E_ + e0 + n];
  }
  #pragma unroll
  for (int j = 0; j < 8; j++) {
    int idx = j * 256 + tid;
    r_bc[j] = xdbc[(size_t)(b * L_ + t0 + (idx >> 5)) * XD_ + R_ + (idx & 31)];
  }

  // branchless parallel lookback over predecessor chunk summaries
  float hs = 0.0f;
  if (c > 0) {
    float pv[NCH_ - 1], sv[NCH_ - 1];
    #pragma unroll
    for (int cc = 0; cc < NCH_ - 1; cc++) {
      int ci = cc < c ? cc : c - 1;
      size_t o = (((size_t)(b * NCH_ + ci) * E_) + e) * N_ + n;
      pv[cc] = Pst[o];
      sv[cc] = Sst[o];
    }
    #pragma unroll
    for (int cc = 0; cc < NCH_ - 1; cc++) {
      bool v = cc < c;
      hs = fmaf(v ? pv[cc] : 1.0f, hs, v ? sv[cc] : 0.0f);
    }
  }

  #pragma unroll
  for (int j = 0; j < 4; j++) {
    int t = j * 16 + el;
    float uf = b2f(r_u[j]);
    s_dtu[t][n] = make_float2(r_dt[j], r_dt[j] * uf);
    s_og[t][n] = make_float2(uf * Dv, b2f(r_g[j]));
  }
  #pragma unroll
  for (int j = 0; j < 8; j++) {
    int idx = j * 256 + tid;
    int t = idx >> 5, col = idx & 31;
    ((float*)&s_bc[t][0])[((col & 15) << 1) + (col >> 4)] = r_bc[j];
  }
  __syncthreads();

  #pragma unroll 8
  for (int t = 0; t < CL_; t++) {
    float2 dtu = s_dtu[t][el];
    float2 bc  = s_bc[t][n];
    float dA = __expf(dtu.x * A);
    hs = fmaf(hs, dA, dtu.y * bc.x);
    float p = row_sum16(hs * bc.y);
    if (n == 0) {
      float2 og = s_og[t][el];
      s_y[t][el] = f2b((p + og.x) * og.y);
    }
  }
  __syncthreads();

  {
    int row = tid >> 2, seg = tid & 3;
    uint2 v = *(const uint2*)&s_y[row][seg * 4];
    *(uint2*)(y + (size_t)(b * L_ + t0 + row) * E_ + e0 + seg * 4) = v;
  }
}

// rs[m] = rsqrt(mean(h[m,:]^2)+eps)
__global__ __launch_bounds__(256) void k_rowscale(const float* __restrict__ h, float* __restrict__ rs) {
  __shared__ float sm[4];
  int m = blockIdx.x, tid = threadIdx.x;
  const float* row = h + (size_t)m * D_;
  float v0 = row[tid], v1 = row[tid + 256], v2 = row[tid + 512];
  float s = block_sum(v0 * v0 + v1 * v1 + v2 * v2, sm);
  if (tid == 0) rs[m] = rsqrtf(s * (1.0f / D_) + EPS_);
}

// partial pool: pooledP[pc][b][d] = sum over the pc-th t-chunk of h*rs
__global__ __launch_bounds__(256) void k_pool(const float* __restrict__ h, const float* __restrict__ rs,
                                              float* __restrict__ pooledP) {
  int d = blockIdx.x * 256 + threadIdx.x;
  int pc = blockIdx.y;
  int b = blockIdx.z;
  int t0 = pc * (L_ / PC_);
  float acc = 0.0f;
  for (int t = t0; t < t0 + L_ / PC_; t++) {
    int m = b * L_ + t;
    acc = fmaf(h[(size_t)m * D_ + d], rs[m], acc);
  }
  pooledP[((size_t)pc * B_ + b) * D_ + d] = acc;
}

// out[b,c]: cooperative LDS reduce of pooledP (coalesced), then wave-dot from LDS.
__global__ __launch_bounds__(256) void k_logits(const float* __restrict__ pooledP, const float* __restrict__ fw,
                                                const float* __restrict__ cw, const float* __restrict__ cb,
                                                float* __restrict__ out) {
  __shared__ float sp[B_ * D_];   // 6 KB
  int tid = threadIdx.x;
  for (int d = tid; d < B_ * D_; d += 256) {
    int b = d / D_, dd = d - b * D_;
    float pd = 0.0f;
    #pragma unroll
    for (int pc = 0; pc < PC_; pc++) pd += pooledP[((size_t)pc * B_ + b) * D_ + dd];
    sp[d] = pd * fw[dd] * (1.0f / L_);
  }
  __syncthreads();
  int wv = tid >> 6, ln = tid & 63;
  for (int p = wv; p < B_ * NC_; p += 4) {
    int b = p / NC_, c = p % NC_;
    float s = 0.0f;
    for (int d = ln; d < D_; d += 64) s = fmaf(sp[b * D_ + d], cw[c * D_ + d], s);
    #pragma unroll
    for (int o = 32; o > 0; o >>= 1) s += __shfl_xor(s, o);
    if (ln == 0) out[p] = s + cb[c];
  }
}

extern "C" void kernel_launch(void* const* d_in, const int* in_sizes, int n_in,
                              void* d_out, int out_size, void* d_ws, size_t ws_size,
                              hipStream_t stream) {
  const float* x       = (const float*)d_in[0];
  const float* proj_w  = (const float*)d_in[1];
  const float* proj_b  = (const float*)d_in[2];
  const float* norm_w  = (const float*)d_in[3];
  const float* in_w    = (const float*)d_in[4];
  const float* conv_w  = (const float*)d_in[5];
  const float* conv_b  = (const float*)d_in[6];
  const float* xproj_w = (const float*)d_in[7];
  const float* dt_w    = (const float*)d_in[8];
  const float* dt_b    = (const float*)d_in[9];
  const float* A_log   = (const float*)d_in[10];
  const float* D_param = (const float*)d_in[11];
  const float* out_w   = (const float*)d_in[12];
  const float* fnorm_w = (const float*)d_in[13];
  const float* cls_w   = (const float*)d_in[14];
  const float* cls_b   = (const float*)d_in[15];
  float* out = (float*)d_out;

  // workspace layout
  float* h      = (float*)d_ws;                         // M*D
  float* xdbc   = h + (size_t)M_ * D_;                  // M*80
  float* dtbuf  = xdbc + (size_t)M_ * XD_;              // M*E fp32 dt
  float* rsb    = dtbuf + (size_t)M_ * E_;              // M
  float* pooledP = rsb + M_;                            // PC*B*D
  float* Pst    = pooledP + (size_t)PC_ * B_ * D_;      // B*NCH*E*N
  float* Sst    = Pst + (size_t)B_ * NCH_ * E_ * N_;    // B*NCH*E*N
  float* xpart  = Sst + (size_t)B_ * NCH_ * E_ * N_;    // KS*M*80
  ushort* proj_bf = (ushort*)(xpart + (size_t)KS_ * M_ * XD_);  // M*2E bf16
  ushort* hn_bf   = proj_bf + (size_t)M_ * E2_;         // M*D
  ushort* y_bf    = hn_bf + (size_t)M_ * D_;            // M*E
  ushort* ub_bf   = y_bf + (size_t)M_ * E_;             // M*E
  ushort* g_bf    = ub_bf + (size_t)M_ * E_;            // M*E
  ushort* xdbc_bf = g_bf + (size_t)M_ * E_;             // M*64
  ushort* xwb     = xdbc_bf + (size_t)M_ * 64;          // NL*80*E
  ushort* dtwb    = xwb + (size_t)NL_ * XD_ * E_;       // NL*E*64
  ushort* in_wb   = dtwb + (size_t)NL_ * E_ * 64;       // NL*E2*D
  ushort* out_wb  = in_wb + (size_t)NL_ * E2_ * D_;     // NL*D*E

  // weight prep + input projection in one dispatch
  k_wprep<<<WB_ + 3 * M_, 256, 0, stream>>>(in_w, out_w, xproj_w, dt_w,
                                            in_wb, out_wb, xwb, dtwb,
                                            x, proj_w, proj_b, h);

  for (int i = 0; i < NL_; i++) {
    k_rmsnorm_bf<<<M_, 256, 0, stream>>>(h, norm_w + i * D_, hn_bf);
    k_gemm_bf<64, 192, 3><<<dim3(E2_ / 192, M_ / 64), 256, 0, stream>>>(
        hn_bf, in_wb + (size_t)i * E2_ * D_, proj_bf, nullptr, D_, E2_);
    k_conv2<<<M_, 384, 0, stream>>>(proj_bf, conv_w + i * E_ * 4, conv_b + i * E_, ub_bf, g_bf);
    k_gemm_x<<<dim3(M_ / 64, KS_), 256, 0, stream>>>(ub_bf, xwb + (size_t)i * XD_ * E_, xpart);
    k_xfin<<<M_ * XD_ / 256, 256, 0, stream>>>(xpart, xdbc, xdbc_bf);
    k_gemm_bf<64, 64, 2><<<dim3(E_ / 64, M_ / 64), 256, 0, stream>>>(
        xdbc_bf, dtwb + (size_t)i * E_ * 64, dtbuf, dt_b + i * E_, 64, E_);
    k_scanA<<<dim3(E_ / 16, B_, NCH_), 256, 0, stream>>>(ub_bf, dtbuf, xdbc,
                                                         A_log + (size_t)i * E_ * N_, Pst, Sst);
    k_scanC<<<dim3(E_ / 16, B_, NCH_), 256, 0, stream>>>(ub_bf, dtbuf, xdbc, g_bf,
                                                         A_log + (size_t)i * E_ * N_, D_param + i * E_,
                                                         Pst, Sst, y_bf);
    k_gemm_bf<64, 64, 1><<<dim3(D_ / 64, M_ / 64), 256, 0, stream>>>(
        y_bf, out_wb + (size_t)i * D_ * E_, h, h, E_, D_);
  }

  k_rowscale<<<M_, 256, 0, stream>>>(h, rsb);
  k_pool<<<dim3(D_ / 256, PC_, B_), 256, 0, stream>>>(h, rsb, pooledP);
  k_logits<<<1, 256, 0, stream>>>(pooledP, fnorm_w, cls_w, cls_b, out);
}